// Round 6
// baseline (692.063 us; speedup 1.0000x reference)
//
#include <hip/hip_runtime.h>

// ---------------- problem constants ----------------
#define NVARS 700
#define MC    5558
#define MAXIT 20

typedef __attribute__((ext_vector_type(8))) short bf16x8;
typedef __attribute__((ext_vector_type(4))) float f32x4;

__device__ __forceinline__ ushort f2bf(float x) {
  unsigned u = __float_as_uint(x);
  return (ushort)((u + 0x7FFFu + ((u >> 16) & 1u)) >> 16);
}

// =====================================================================
// qinv kernel (unchanged): Qt[k*100+i], k in [0,101)
// =====================================================================
__device__ __forceinline__ double Wfun(int a, int b) {
  if (a < 0 || a > 99 || b < 0 || b > 99) return 0.0;
  int d = a - b; if (d < 0) d = -d;
  int l = a < b ? a : b;
  const double iT2 = 2500.0;
  const double iT4 = 6250000.0;
  double w = 0.0;
  if (d == 0) {
    w = 3.0;
    w += 2.0 * iT2 * (double)((a <= 98 ? 1 : 0) + (a >= 1 ? 1 : 0));
    double dd = (double)(((a - 2) >= 0 && (a - 2) <= 97) ? 1 : 0)
              + 4.0 * (double)(((a - 1) >= 0 && (a - 1) <= 97) ? 1 : 0)
              + (double)((a <= 97) ? 1 : 0);
    w += 2.0 * iT4 * dd;
  } else if (d == 1) {
    w = -2.0 * iT2;
    double dd = -2.0 * (double)(((l - 1) >= 0 && (l - 1) <= 97) ? 1 : 0)
                - 2.0 * (double)((l <= 97) ? 1 : 0);
    w += 2.0 * iT4 * dd;
  } else if (d == 2) {
    w = 2.0 * iT4 * (double)((l <= 97) ? 1 : 0);
  }
  return w;
}

__global__ __launch_bounds__(128) void qinv_kernel(double* __restrict__ zbuf,
                                                   double* __restrict__ cid,
                                                   float* __restrict__ Qt)
{
  __shared__ double Bb[100][4];
  __shared__ double Gb[100][4];
  __shared__ double invd[100];
  int tid = threadIdx.x;
  for (int q = tid; q < 400; q += 128) {
    int i = q >> 2, k = q & 3;
    int j = i - k;
    double v = 0.0;
    if (j >= 0) {
      v = Wfun(i, j) - Wfun(i + 1, j) - Wfun(i, j + 1) + Wfun(i + 1, j + 1);
      if (k == 0) v += 2.0 * 0.02 * 0.02;
    }
    Bb[i][k] = v;
  }
  __syncthreads();
  if (tid == 0) {
    for (int i = 0; i < 100; ++i) {
      for (int k = 3; k >= 1; --k) {
        int j = i - k;
        if (j < 0) { Gb[i][k] = 0.0; continue; }
        double s = Bb[i][k];
        for (int m = k + 1; m <= 3; ++m)
          if (m <= i) s -= Gb[i][m] * Gb[j][m - k];
        Gb[i][k] = s * invd[j];
      }
      double s = Bb[i][0];
      for (int m = 1; m <= 3; ++m)
        if (m <= i) s -= Gb[i][m] * Gb[i][m];
      double g = sqrt(s);
      Gb[i][0] = g;
      invd[i] = 1.0 / g;
    }
  }
  __syncthreads();
  if (tid < 100) {
    int c = tid;
    double z0 = 0, z1 = 0, z2 = 0;
    for (int i = 0; i < 100; ++i) {
      double v = (i == c ? 1.0 : 0.0) - (i == (c - 1) ? 1.0 : 0.0);
      double s = v - Gb[i][1] * z0 - Gb[i][2] * z1 - Gb[i][3] * z2;
      double z = s * invd[i];
      zbuf[i * 128 + c] = z;
      z2 = z1; z1 = z0; z0 = z;
    }
    double y0 = 0, y1 = 0, y2 = 0;
    for (int i = 99; i >= 0; --i) {
      double s = zbuf[i * 128 + c];
      if (i + 1 <= 99) s -= Gb[i + 1][1] * y0;
      if (i + 2 <= 99) s -= Gb[i + 2][2] * y1;
      if (i + 3 <= 99) s -= Gb[i + 3][3] * y2;
      double y = s * invd[i];
      zbuf[i * 128 + c] = y;
      y2 = y1; y1 = y0; y0 = y;
    }
    double ym = 0.0;
    for (int i = 0; i < 100; ++i) {
      double y = zbuf[i * 128 + c];
      cid[i * 100 + c] = y - ym;
      ym = y;
    }
  }
  __syncthreads();
  double invs = 1.0 / cid[0];
  for (int q = tid; q < 101 * 100; q += 128) {
    int k = q / 100, i = q - (q / 100) * 100;
    double val;
    if (k < 100) val = cid[i * 100 + k] - cid[i * 100] * cid[k] * invs;
    else         val = cid[i * 100] * invs;
    Qt[k * 100 + i] = (float)val;
  }
}

// =====================================================================
// quantiles (unchanged)
// =====================================================================
__global__ __launch_bounds__(256) void quantile_kernel(const float* __restrict__ in,
                                                       float* __restrict__ med,
                                                       float* __restrict__ rinv)
{
  __shared__ float v[1024];
  int c = blockIdx.x, tid = threadIdx.x;
  for (int i = tid; i < 1024; i += 256) v[i] = in[i * NVARS + c];
  __syncthreads();
  for (int k = 2; k <= 1024; k <<= 1) {
    for (int j = k >> 1; j > 0; j >>= 1) {
      for (int i = tid; i < 1024; i += 256) {
        int ixj = i ^ j;
        if (ixj > i) {
          float a = v[i], b2 = v[ixj];
          bool up = ((i & k) == 0);
          if ((a > b2) == up) { v[i] = b2; v[ixj] = a; }
        }
      }
      __syncthreads();
    }
  }
  if (tid == 0) {
    float m  = v[511];
    float q1 = v[255] + 0.75f * (v[256] - v[255]);
    float q3 = v[767] + 0.25f * (v[768] - v[767]);
    float iq = q3 - q1;
    if (iq == 0.f) iq = 1.f;
    med[c] = m;
    rinv[c] = 1.f / iq;
  }
}

// ---- normalize + split to bf16 hi/lo, padded K=704 ----
__global__ __launch_bounds__(256) void normalize_split(const float* __restrict__ in,
                                                       const float* __restrict__ med,
                                                       const float* __restrict__ rinv,
                                                       ushort* __restrict__ Ah,
                                                       ushort* __restrict__ Al)
{
  int idx = blockIdx.x * 256 + threadIdx.x;
  if (idx >= 1024 * 704) return;
  int r = idx / 704, c = idx - r * 704;
  float v = 0.f;
  if (c < 700) v = (in[r * NVARS + c] - med[c]) * rinv[c];
  ushort h = f2bf(v);
  float fh = __uint_as_float(((unsigned)h) << 16);
  Ah[idx] = h;
  Al[idx] = f2bf(v - fh);
}

// ---- transpose + split: dst[n][k] = src[k][col0+n], zero padded ----
__global__ __launch_bounds__(256) void tsplit(const float* __restrict__ src,
                                              int srows, int scols, int sld, int col0,
                                              ushort* __restrict__ dh,
                                              ushort* __restrict__ dl, int dld)
{
  __shared__ float tile[32][33];
  int k0 = blockIdx.x * 32, n0 = blockIdx.y * 32;
  int tx = threadIdx.x, ty = threadIdx.y;   // (32, 8)
  for (int i = ty; i < 32; i += 8) {
    int k = k0 + i, c = col0 + n0 + tx;
    tile[i][tx] = (k < srows && c < scols) ? src[(size_t)k * sld + c] : 0.f;
  }
  __syncthreads();
  for (int i = ty; i < 32; i += 8) {
    int n = n0 + i, k = k0 + tx;
    float v = tile[tx][i];
    ushort h = f2bf(v);
    float fh = __uint_as_float(((unsigned)h) << 16);
    dh[(size_t)n * dld + k] = h;
    dl[(size_t)n * dld + k] = f2bf(v - fh);
  }
}

// =====================================================================
// MFMA GEMM, bf16 hi/lo split (3 products ~= f32 accuracy).
// C[M x Np] = A[M x Kp] @ B^T, B n-major [Np][Kp]. BK=32, 256 thr, 4 waves 2x2.
// MODE 0: Cf = acc + bias (guarded) ; MODE 1: relu(acc+bias) -> hi/lo bf16
// =====================================================================
template <int BM, int BN, int MODE>
__global__ __launch_bounds__(256) void gemm_mfma(
    const ushort* __restrict__ Agh, const ushort* __restrict__ Agl,
    const ushort* __restrict__ Bgh, const ushort* __restrict__ Bgl,
    const float* __restrict__ bias, int bias_n,
    float* __restrict__ Cf, ushort* __restrict__ Chi, ushort* __restrict__ Clo,
    int Kp, int ldc)
{
  constexpr int ACH = BM * 4 / 256;
  constexpr int BCH = BN * 4 / 256;
  constexpr int MF = BM / 32;
  constexpr int NF = BN / 32;
  __shared__ __align__(16) ushort Ash[BM * 40];
  __shared__ __align__(16) ushort Asl[BM * 40];
  __shared__ __align__(16) ushort Bsh[BN * 40];
  __shared__ __align__(16) ushort Bsl[BN * 40];

  const int t = threadIdx.x;
  const size_t bm = (size_t)blockIdx.y * BM;
  const size_t bn = (size_t)blockIdx.x * BN;

  size_t aoff[ACH]; int awo[ACH];
#pragma unroll
  for (int s = 0; s < ACH; ++s) {
    int slot = t * ACH + s, row = slot >> 2, ch = slot & 3;
    aoff[s] = (bm + row) * (size_t)Kp + ch * 8;
    awo[s] = row * 40 + ch * 8;
  }
  size_t boff[BCH]; int bwo[BCH];
#pragma unroll
  for (int s = 0; s < BCH; ++s) {
    int slot = t * BCH + s, row = slot >> 2, ch = slot & 3;
    boff[s] = (bn + row) * (size_t)Kp + ch * 8;
    bwo[s] = row * 40 + ch * 8;
  }

  const int w = t >> 6, lane = t & 63;
  const int wr = w >> 1, wc = w & 1;
  const int fr = lane & 15, fg = lane >> 4;

  f32x4 acc[MF][NF];
#pragma unroll
  for (int a = 0; a < MF; ++a)
#pragma unroll
    for (int b = 0; b < NF; ++b) acc[a][b] = (f32x4){0.f, 0.f, 0.f, 0.f};

  const int nk = Kp >> 5;
  uint4 rAh[ACH], rAl[ACH], rBh[BCH], rBl[BCH];
#pragma unroll
  for (int s = 0; s < ACH; ++s) { rAh[s] = *(const uint4*)(Agh + aoff[s]); rAl[s] = *(const uint4*)(Agl + aoff[s]); }
#pragma unroll
  for (int s = 0; s < BCH; ++s) { rBh[s] = *(const uint4*)(Bgh + boff[s]); rBl[s] = *(const uint4*)(Bgl + boff[s]); }

  for (int kt = 0;; ++kt) {
    __syncthreads();
#pragma unroll
    for (int s = 0; s < ACH; ++s) { *(uint4*)&Ash[awo[s]] = rAh[s]; *(uint4*)&Asl[awo[s]] = rAl[s]; }
#pragma unroll
    for (int s = 0; s < BCH; ++s) { *(uint4*)&Bsh[bwo[s]] = rBh[s]; *(uint4*)&Bsl[bwo[s]] = rBl[s]; }
    __syncthreads();
    if (kt + 1 < nk) {
      int ko = (kt + 1) * 32;
#pragma unroll
      for (int s = 0; s < ACH; ++s) { rAh[s] = *(const uint4*)(Agh + aoff[s] + ko); rAl[s] = *(const uint4*)(Agl + aoff[s] + ko); }
#pragma unroll
      for (int s = 0; s < BCH; ++s) { rBh[s] = *(const uint4*)(Bgh + boff[s] + ko); rBl[s] = *(const uint4*)(Bgl + boff[s] + ko); }
    }
    bf16x8 fah[MF], fal[MF], fbh[NF], fbl[NF];
#pragma unroll
    for (int mf = 0; mf < MF; ++mf) {
      int off = (wr * (BM / 2) + mf * 16 + fr) * 40 + fg * 8;
      fah[mf] = *(const bf16x8*)&Ash[off];
      fal[mf] = *(const bf16x8*)&Asl[off];
    }
#pragma unroll
    for (int nf = 0; nf < NF; ++nf) {
      int off = (wc * (BN / 2) + nf * 16 + fr) * 40 + fg * 8;
      fbh[nf] = *(const bf16x8*)&Bsh[off];
      fbl[nf] = *(const bf16x8*)&Bsl[off];
    }
#pragma unroll
    for (int mf = 0; mf < MF; ++mf)
#pragma unroll
      for (int nf = 0; nf < NF; ++nf) {
        acc[mf][nf] = __builtin_amdgcn_mfma_f32_16x16x32_bf16(fah[mf], fbh[nf], acc[mf][nf], 0, 0, 0);
        acc[mf][nf] = __builtin_amdgcn_mfma_f32_16x16x32_bf16(fah[mf], fbl[nf], acc[mf][nf], 0, 0, 0);
        acc[mf][nf] = __builtin_amdgcn_mfma_f32_16x16x32_bf16(fal[mf], fbh[nf], acc[mf][nf], 0, 0, 0);
      }
    if (kt + 1 >= nk) break;
  }

#pragma unroll
  for (int mf = 0; mf < MF; ++mf)
#pragma unroll
    for (int nf = 0; nf < NF; ++nf) {
      int col = (int)bn + wc * (BN / 2) + nf * 16 + fr;
      int rowb = (int)bm + wr * (BM / 2) + mf * 16 + fg * 4;
#pragma unroll
      for (int j = 0; j < 4; ++j) {
        int row = rowb + j;
        float v = acc[mf][nf][j];
        if (MODE == 0) {
          float bv = (col < bias_n) ? bias[col] : 0.f;
          Cf[(size_t)row * ldc + col] = v + bv;
        } else {
          float r = fmaxf(v + bias[col], 0.f);
          ushort h = f2bf(r);
          float fh = __uint_as_float(((unsigned)h) << 16);
          Chi[(size_t)row * ldc + col] = h;
          Clo[(size_t)row * ldc + col] = f2bf(r - fh);
        }
      }
    }
}

// =====================================================================
// fallback path: f32 normalize + SIMT GEMM
// =====================================================================
__global__ __launch_bounds__(256) void normalize_kernel(const float* __restrict__ in,
                                                        const float* __restrict__ med,
                                                        const float* __restrict__ rinv,
                                                        float* __restrict__ An)
{
  int idx = blockIdx.x * 256 + threadIdx.x;
  if (idx < 1024 * NVARS) {
    int c = idx % NVARS;
    An[idx] = (in[idx] - med[c]) * rinv[c];
  }
}

template <bool RELU>
__global__ __launch_bounds__(256) void gemm_kernel(const float* __restrict__ A, int lda,
                                                   const float* __restrict__ B, int ldb,
                                                   const float* __restrict__ bias,
                                                   float* __restrict__ C, int ldc,
                                                   int N, int K)
{
  __shared__ __align__(16) float As[16][68];
  __shared__ __align__(16) float Bs[16][64];
  int tid = threadIdx.x;
  int bm = blockIdx.y * 64, bn = blockIdx.x * 64;
  int tx = tid & 15, ty = tid >> 4;
  float acc[4][4] = {};
  for (int k0 = 0; k0 < K; k0 += 16) {
    {
      int q = tid * 4;
      int m = q >> 4, kk = q & 15;
      const float* ap = A + (size_t)(bm + m) * lda + k0;
#pragma unroll
      for (int s2 = 0; s2 < 4; ++s2) {
        int kc = kk + s2;
        As[kc][m] = (k0 + kc < K) ? ap[kc] : 0.f;
      }
    }
#pragma unroll
    for (int s2 = 0; s2 < 4; ++s2) {
      int q = tid + s2 * 256;
      int kk = q >> 6, n = q & 63;
      float val = 0.f;
      if (k0 + kk < K && bn + n < N) val = B[(size_t)(k0 + kk) * ldb + bn + n];
      Bs[kk][n] = val;
    }
    __syncthreads();
#pragma unroll
    for (int kk = 0; kk < 16; ++kk) {
      float4 av = *reinterpret_cast<const float4*>(&As[kk][ty * 4]);
      float4 bv = *reinterpret_cast<const float4*>(&Bs[kk][tx * 4]);
      acc[0][0] += av.x * bv.x; acc[0][1] += av.x * bv.y; acc[0][2] += av.x * bv.z; acc[0][3] += av.x * bv.w;
      acc[1][0] += av.y * bv.x; acc[1][1] += av.y * bv.y; acc[1][2] += av.y * bv.z; acc[1][3] += av.y * bv.w;
      acc[2][0] += av.z * bv.x; acc[2][1] += av.z * bv.y; acc[2][2] += av.z * bv.z; acc[2][3] += av.z * bv.w;
      acc[3][0] += av.w * bv.x; acc[3][1] += av.w * bv.y; acc[3][2] += av.w * bv.z; acc[3][3] += av.w * bv.w;
    }
    __syncthreads();
  }
#pragma unroll
  for (int i = 0; i < 4; ++i) {
    int m = bm + ty * 4 + i;
#pragma unroll
    for (int j = 0; j < 4; ++j) {
      int n = bn + tx * 4 + j;
      if (n < N) {
        float r = acc[i][j] + bias[n];
        if (RELU) r = fmaxf(r, 0.f);
        C[(size_t)m * ldc + n] = r;
      }
    }
  }
}

// =====================================================================
// solver v4: v3.1 + DPP scans (no ds_bpermute), readlane broadcasts,
// combine-pass folded into phase C (2 barriers/iter).
// =====================================================================
__device__ __forceinline__ float rdlane(float v, int lane) {
  return __int_as_float(__builtin_amdgcn_readlane(__float_as_int(v), lane));
}

// wave64 inclusive scan, pure VALU via DPP (row_shr + row_bcast), no DS ops
__device__ __forceinline__ float iscan(float v) {
  float f = v;
  int t;
  t = __builtin_amdgcn_update_dpp(0, __float_as_int(f), 0x111, 0xf, 0xf, false); // row_shr:1
  f += __int_as_float(t);
  t = __builtin_amdgcn_update_dpp(0, __float_as_int(f), 0x112, 0xf, 0xf, false); // row_shr:2
  f += __int_as_float(t);
  t = __builtin_amdgcn_update_dpp(0, __float_as_int(f), 0x114, 0xf, 0xf, false); // row_shr:4
  f += __int_as_float(t);
  t = __builtin_amdgcn_update_dpp(0, __float_as_int(f), 0x118, 0xf, 0xf, false); // row_shr:8
  f += __int_as_float(t);
  t = __builtin_amdgcn_update_dpp(0, __float_as_int(f), 0x142, 0xa, 0xf, false); // row_bcast:15 -> rows 1,3
  f += __int_as_float(t);
  t = __builtin_amdgcn_update_dpp(0, __float_as_int(f), 0x143, 0xc, 0xf, false); // row_bcast:31 -> rows 2,3
  f += __int_as_float(t);
  return f;
}

struct TR {
  float vp0, vm0, vp1, vm1;
  float ap0, am0, ap1, am1;
  float jp0, jm0, jp1, jm1;
  float pp0, pm0, pp1, pm1;
};

// ws = relu(tm)-relu(tp);  wr = relu(-tp)-relu(-tm) = (tm-tp)-ws  (exact)
__device__ __forceinline__ void wpair(float tp, float tm, float& ws, float& wr) {
  float a = fmaxf(tp, 0.f), b = fmaxf(tm, 0.f);
  ws = b - a;
  wr = (tm - tp) - ws;
}

// A^T stencil for both variants at idx0=l and idx1=64+l
__device__ __forceinline__ void w_phase(const TR& t, int l, bool hi, float dth,
                                        float& os0, float& os1, float& or0, float& or1)
{
  float vs0, vr0, vs1, vr1, ys0, yr0, ys1, yr1;
  float zs0, zr0, zs1, zr1, ps0, pr0, ps1, pr1;
  wpair(t.vp0, t.vm0, vs0, vr0);
  wpair(t.ap0, t.am0, ys0, yr0);
  wpair(t.jp0, t.jm0, zs0, zr0);
  wpair(t.pp0, t.pm0, ps0, pr0);
  if (hi) { wpair(t.vp1, t.vm1, vs1, vr1); wpair(t.pp1, t.pm1, ps1, pr1); }
  else    { vs1 = vr1 = ps1 = pr1 = 0.f; }
  if (hi && l <= 34) { wpair(t.ap1, t.am1, ys1, yr1); } else { ys1 = yr1 = 0.f; }
  if (hi && l <= 33) { wpair(t.jp1, t.jm1, zs1, zr1); } else { zs1 = zr1 = 0.f; }

  const int lm1 = (l + 63) & 63, lm2 = (l + 62) & 63;
  float u1ys0 = __shfl(ys0, lm1), u1ys1 = __shfl(ys1, lm1);
  float u1zs0 = __shfl(zs0, lm1), u1zs1 = __shfl(zs1, lm1);
  float u2zs0 = __shfl(zs0, lm2), u2zs1 = __shfl(zs1, lm2);
  float u1yr0 = __shfl(yr0, lm1), u1yr1 = __shfl(yr1, lm1);
  float u1zr0 = __shfl(zr0, lm1), u1zr1 = __shfl(zr1, lm1);
  float u2zr0 = __shfl(zr0, lm2), u2zr1 = __shfl(zr1, lm2);

  float pa0s = ps0 + dth;
  float pa1s = hi ? ps1 + dth : 0.f;
  float pa0r = pr0;
  float pa1r = hi ? pr1 : 0.f;
  float s0s = iscan(pa0s);
  float s0r = iscan(pa0r);
  float tots = rdlane(s0s, 63), totr = rdlane(s0r, 63);
  float s1s = iscan(pa1s) + tots;
  float s1r = iscan(pa1r) + totr;
  float Ss = rdlane(s1s, 35), Sr = rdlane(s1r, 35);
  float rc0s = Ss - s0s + pa0s, rc1s = Ss - s1s + pa1s;
  float rc0r = Sr - s0r + pa0r, rc1r = Sr - s1r + pa1r;

  float ym1s0 = l ? u1ys0 : 0.f, zm1s0 = l ? u1zs0 : 0.f, zm2s0 = (l >= 2) ? u2zs0 : 0.f;
  float ym1r0 = l ? u1yr0 : 0.f, zm1r0 = l ? u1zr0 : 0.f, zm2r0 = (l >= 2) ? u2zr0 : 0.f;
  os0 = vs0 + 50.f * (ym1s0 - ys0) + 2500.f * (zm2s0 - 2.f * zm1s0 + zs0) + 0.02f * rc0s;
  or0 = vr0 + 50.f * (ym1r0 - yr0) + 2500.f * (zm2r0 - 2.f * zm1r0 + zr0) + 0.02f * rc0r;
  float ym1s1 = l ? u1ys1 : u1ys0, zm1s1 = l ? u1zs1 : u1zs0, zm2s1 = (l >= 2) ? u2zs1 : u2zs0;
  float ym1r1 = l ? u1yr1 : u1yr0, zm1r1 = l ? u1zr1 : u1zr0, zm2r1 = (l >= 2) ? u2zr1 : u2zr0;
  os1 = vs1 + 50.f * (ym1s1 - ys1) + 2500.f * (zm2s1 - 2.f * zm1s1 + zs1) + 0.02f * rc1s;
  or1 = vr1 + 50.f * (ym1r1 - yr1) + 2500.f * (zm2r1 - 2.f * zm1r1 + zr1) + 0.02f * rc1r;
}

__global__ __launch_bounds__(448, 4) void solver_kernel(const float* __restrict__ out2,
                                                        const float* __restrict__ input,
                                                        const float* __restrict__ theta,
                                                        const float* __restrict__ vstart,
                                                        const float* __restrict__ Qtg,
                                                        float* __restrict__ out, int ldo)
{
  __shared__ __align__(16) float ru_t[101][12];
  __shared__ float pm[4][700];
  __shared__ float part[7][20][3];
  __shared__ float prfp[40];

  const int b = blockIdx.x, tid = threadIdx.x;
  const int d = tid >> 6, l = tid & 63;
  const bool hi = (l < 36);
  const int i2 = 64 + l;
  const float th = theta[b];
  const float dth = (d == 3) ? -2.f * th : 0.f;
  const float bp  = (d <= 3) ? (3.14f - th) : (3.14f + th);
  const float bm2 = (d <  3) ? (3.14f - th) : (3.14f + th);
  const float* orow = out2 + (size_t)b * ldo;
  const float* srow = orow + 700;

  float lam0 = orow[d * 100 + l];
  float xs0  = input[(size_t)b * NVARS + d * 100 + l];
  float lam1 = hi ? orow[d * 100 + i2] : 0.f;
  float xs1  = hi ? input[(size_t)b * NVARS + d * 100 + i2] : 0.f;

  TR t;
  {
    const int vb = d * 200, ab = 1400 + d * 198, jb = 2786 + d * 196, pb = 4158 + d * 200;
    t.vp0 = fmaxf(srow[vb + l], 0.f);        t.vm0 = fmaxf(srow[vb + 100 + l], 0.f);
    t.ap0 = fmaxf(srow[ab + l], 0.f);        t.am0 = fmaxf(srow[ab + 99 + l], 0.f);
    t.jp0 = fmaxf(srow[jb + l], 0.f);        t.jm0 = fmaxf(srow[jb + 98 + l], 0.f);
    t.pp0 = fmaxf(srow[pb + l], 0.f);        t.pm0 = fmaxf(srow[pb + 100 + l], 0.f);
    t.vp1 = hi        ? fmaxf(srow[vb + i2], 0.f)      : 0.f;
    t.vm1 = hi        ? fmaxf(srow[vb + 100 + i2], 0.f) : 0.f;
    t.ap1 = (l <= 34) ? fmaxf(srow[ab + i2], 0.f)      : 0.f;
    t.am1 = (l <= 34) ? fmaxf(srow[ab + 99 + i2], 0.f) : 0.f;
    t.jp1 = (l <= 33) ? fmaxf(srow[jb + i2], 0.f)      : 0.f;
    t.jm1 = (l <= 33) ? fmaxf(srow[jb + 98 + i2], 0.f) : 0.f;
    t.pp1 = hi        ? fmaxf(srow[pb + i2], 0.f)      : 0.f;
    t.pm1 = hi        ? fmaxf(srow[pb + 100 + i2], 0.f) : 0.f;
  }
  if (l == 0) ru_t[100][d] = vstart[b * 7 + d];

  // pre-loop: ru from s0 (res-part is exactly zero here)
  {
    float os0, os1, or0, or1;
    w_phase(t, l, hi, dth, os0, os1, or0, or1);
    ru_t[l][d] = lam0 + xs0 + os0;
    if (hi) ru_t[i2][d] = lam1 + xs1 + os1;
  }

  for (int it = 0; it < MAXIT; ++it) {
    __syncthreads();   // barrier 1: ru ready
    // ---- phase B: xi partials = Qtop @ [ru; v] ----
    {
      int kc = tid / 112, r = tid - kc * 112;
      if (r < 100) {
        float acc[7] = {0.f, 0.f, 0.f, 0.f, 0.f, 0.f, 0.f};
        int k0 = kc * 25, k1 = (kc == 3) ? 101 : k0 + 25;
        for (int k = k0; k < k1; ++k) {
          float qv = Qtg[k * 100 + r];
          float4 ra = *reinterpret_cast<const float4*>(&ru_t[k][0]);
          float4 rb = *reinterpret_cast<const float4*>(&ru_t[k][4]);
          acc[0] += qv * ra.x; acc[1] += qv * ra.y; acc[2] += qv * ra.z; acc[3] += qv * ra.w;
          acc[4] += qv * rb.x; acc[5] += qv * rb.y; acc[6] += qv * rb.z;
        }
#pragma unroll
        for (int dd = 0; dd < 7; ++dd) pm[kc][dd * 100 + r] = acc[dd];
      }
    }
    __syncthreads();   // barrier 2: partials ready

    // ---- phase C: fold partials -> xi; t = b - A xi (regs); r2, ds2 ----
    float r2 = 0.f, ds2 = 0.f, dl2 = 0.f;
    {
      const int a0 = d * 100 + l;
      float x0 = pm[0][a0] + pm[1][a0] + pm[2][a0] + pm[3][a0];
      float x1 = 0.f;
      if (hi) {
        const int a1 = d * 100 + i2;
        x1 = pm[0][a1] + pm[1][a1] + pm[2][a1] + pm[3][a1];
      }
      const int lp1 = (l + 1) & 63, lp2 = (l + 2) & 63;
      float d1x0 = __shfl(x0, lp1), d1x1 = __shfl(x1, lp1);
      float d2x0 = __shfl(x0, lp2), d2x1 = __shfl(x1, lp2);
      float xp1_0 = (l == 63) ? d1x1 : d1x0;
      float xp2_0 = (l >= 62) ? d2x1 : d2x0;
      float xp1_1 = d1x1, xp2_1 = d2x1;
      float c0 = iscan(x0);
      float tt = rdlane(c0, 63);
      float c1 = iscan(hi ? x1 : 0.f) + tt;
#define NU(tp_, tm_, np_, nm_) { \
      float sop = fmaxf(tp_, 0.f), som = fmaxf(tm_, 0.f); \
      float snp = fmaxf(np_, 0.f), snm = fmaxf(nm_, 0.f); \
      float e1 = sop - snp, e2 = som - snm; ds2 += e1 * e1 + e2 * e2; \
      float q1 = snp - (np_), q2 = snm - (nm_); r2 += q1 * q1 + q2 * q2; \
      tp_ = np_; tm_ = nm_; }
      { float np = 1.f - x0, nm = 1.f + x0; NU(t.vp0, t.vm0, np, nm) }
      { float a = 50.f * (xp1_0 - x0); float np = 2.f - a, nm = 2.f + a; NU(t.ap0, t.am0, np, nm) }
      { float j = 2500.f * (xp2_0 - 2.f * xp1_0 + x0); float np = 5.f - j, nm = 5.f + j; NU(t.jp0, t.jm0, np, nm) }
      { float np = bp - 0.02f * c0, nm = bm2 + 0.02f * c0; NU(t.pp0, t.pm0, np, nm) }
      if (hi) {
        { float np = 1.f - x1, nm = 1.f + x1; NU(t.vp1, t.vm1, np, nm) }
        { float np = bp - 0.02f * c1, nm = bm2 + 0.02f * c1; NU(t.pp1, t.pm1, np, nm) }
      }
      if (l <= 34) { float a = 50.f * (xp1_1 - x1); float np = 2.f - a, nm = 2.f + a; NU(t.ap1, t.am1, np, nm) }
      if (l <= 33) { float j = 2500.f * (xp2_1 - 2.f * xp1_1 + x1); float np = 5.f - j, nm = 5.f + j; NU(t.jp1, t.jm1, np, nm) }
#undef NU
    }

    // ---- merged phase W: lam -= g (this iter), then ru for next iter ----
    {
      float os0, os1, or0, or1;
      w_phase(t, l, hi, dth, os0, os1, or0, or1);
      lam0 -= or0; dl2 += or0 * or0;
      ru_t[l][d] = lam0 + xs0 + os0;
      if (hi) {
        lam1 -= or1; dl2 += or1 * or1;
        ru_t[i2][d] = lam1 + xs1 + os1;
      }
    }

    // ---- per-wave norm reduce via DPP scan (total lands in lane 63) ----
    r2 = iscan(r2); ds2 = iscan(ds2); dl2 = iscan(dl2);
    if (l == 63) { part[d][it][0] = r2; part[d][it][1] = ds2; part[d][it][2] = dl2; }
  }

  __syncthreads();
  {
    const int a0 = d * 100 + l;
    float x0 = pm[0][a0] + pm[1][a0] + pm[2][a0] + pm[3][a0];
    float* xout = out + (size_t)b * NVARS + d * 100;
    xout[l] = x0;
    if (hi) {
      const int a1 = d * 100 + i2;
      xout[i2] = pm[0][a1] + pm[1][a1] + pm[2][a1] + pm[3][a1];
    }
  }
  if (tid < 20) {
    int it = tid;
    float R2 = 0.f, DS2 = 0.f, DL2 = 0.f;
    for (int dd = 0; dd < 7; ++dd) {
      R2 += part[dd][it][0]; DS2 += part[dd][it][1]; DL2 += part[dd][it][2];
    }
    float pr = sqrtf(R2), fp = sqrtf(DL2) + sqrtf(DS2);
    out[718848 + it * 1024 + b] = pr;
    out[739328 + it * 1024 + b] = fp;
    prfp[it] = pr; prfp[20 + it] = fp;
  }
  __syncthreads();
  if (tid == 0) {
    float ap = 0.f, af = 0.f;
    for (int it = 0; it < 20; ++it) { ap += prfp[it]; af += prfp[20 + it]; }
    out[716800 + b] = af / 20.f;
    out[717824 + b] = ap / 20.f;
  }
}

// =====================================================================
extern "C" void kernel_launch(void* const* d_in, const int* in_sizes, int n_in,
                              void* d_out, int out_size, void* d_ws, size_t ws_size,
                              hipStream_t stream) {
  (void)in_sizes; (void)n_in; (void)out_size;
  const float* input  = (const float*)d_in[0];
  const float* theta  = (const float*)d_in[1];
  const float* vstart = (const float*)d_in[2];
  const float* W1     = (const float*)d_in[3];
  const float* b1     = (const float*)d_in[4];
  const float* W2     = (const float*)d_in[5];
  const float* b2     = (const float*)d_in[6];
  float* out = (float*)d_out;

  double* wsd  = (double*)d_ws;
  double* zbuf = wsd;
  double* cid  = wsd + 12800;
  float* wsf  = (float*)d_ws;
  float* Qt   = wsf + 45600;
  float* med  = wsf + 55704;
  float* rinv = wsf + 56408;

  hipLaunchKernelGGL(qinv_kernel, dim3(1), dim3(128), 0, stream, zbuf, cid, Qt);
  hipLaunchKernelGGL(quantile_kernel, dim3(700), dim3(256), 0, stream, input, med, rinv);

  const size_t HHI = 57112, HLO = 581400, W2TH = 1105688, W2TL = 4316952,
               OUT2 = 7528216, NEED = 13950744;
  const size_t ANH = OUT2, ANL = OUT2 + 360448, W1TH = OUT2 + 720896, W1TL = OUT2 + 1081344;

  if (ws_size >= NEED * 4ull) {
    ushort* an_h  = (ushort*)(wsf + ANH);
    ushort* an_l  = (ushort*)(wsf + ANL);
    ushort* w1t_h = (ushort*)(wsf + W1TH);
    ushort* w1t_l = (ushort*)(wsf + W1TL);
    ushort* h_h   = (ushort*)(wsf + HHI);
    ushort* h_l   = (ushort*)(wsf + HLO);
    ushort* w2t_h = (ushort*)(wsf + W2TH);
    ushort* w2t_l = (ushort*)(wsf + W2TL);
    float*  out2  = wsf + OUT2;

    hipLaunchKernelGGL(normalize_split, dim3((1024 * 704 + 255) / 256), dim3(256), 0, stream,
                       input, med, rinv, an_h, an_l);
    hipLaunchKernelGGL(tsplit, dim3(22, 32), dim3(32, 8), 0, stream,
                       W1, 700, 1024, 1024, 0, w1t_h, w1t_l, 704);
    hipLaunchKernelGGL(tsplit, dim3(32, 196), dim3(32, 8), 0, stream,
                       W2, 1024, 6958, 6958, 700, w2t_h, w2t_l, 1024);
    hipLaunchKernelGGL((gemm_mfma<128, 128, 1>), dim3(8, 8), dim3(256), 0, stream,
                       an_h, an_l, w1t_h, w1t_l, b1, 1024,
                       (float*)nullptr, h_h, h_l, 704, 1024);
    hipLaunchKernelGGL((gemm_mfma<128, 128, 0>), dim3(49, 8), dim3(256), 0, stream,
                       h_h, h_l, w2t_h, w2t_l, b2 + 700, 6258,
                       out2, (ushort*)nullptr, (ushort*)nullptr, 1024, 6272);
    hipLaunchKernelGGL(solver_kernel, dim3(1024), dim3(448), 0, stream,
                       out2, input, theta, vstart, Qt, out, 6272);
  } else {
    float* An   = wsf + 57112;
    float* h    = wsf + 773912;
    float* out2 = wsf + 1822488;
    if (ws_size < (size_t)(1822488 + 6408192) * 4) return;
    hipLaunchKernelGGL(normalize_kernel, dim3(2800), dim3(256), 0, stream, input, med, rinv, An);
    hipLaunchKernelGGL((gemm_kernel<true>), dim3(16, 16), dim3(256), 0, stream,
                       An, NVARS, W1, 1024, b1, h, 1024, 1024, NVARS);
    hipLaunchKernelGGL((gemm_kernel<false>), dim3(98, 16), dim3(256), 0, stream,
                       h, 1024, W2 + 700, 6958, b2 + 700, out2, 6258, 6258, 1024);
    hipLaunchKernelGGL(solver_kernel, dim3(1024), dim3(448), 0, stream,
                       out2, input, theta, vstart, Qt, out, 6258);
  }
}

// Round 7
// 643.561 us; speedup vs baseline: 1.0754x; 1.0754x over previous
//
#include <hip/hip_runtime.h>

// ---------------- problem constants ----------------
#define NVARS 700
#define MC    5558
#define MAXIT 20

typedef __attribute__((ext_vector_type(8))) short bf16x8;
typedef __attribute__((ext_vector_type(4))) float f32x4;

__device__ __forceinline__ ushort f2bf(float x) {
  unsigned u = __float_as_uint(x);
  return (ushort)((u + 0x7FFFu + ((u >> 16) & 1u)) >> 16);
}

// =====================================================================
// qinv v2: LDS-resident triangular solves (no global zbuf round-trips).
// Outputs QtT[i*112 + k] = Qd_inv_top[i][k] (k<=100; 101..111 zero pad).
// =====================================================================
__device__ __forceinline__ double Wfun(int a, int b) {
  if (a < 0 || a > 99 || b < 0 || b > 99) return 0.0;
  int d = a - b; if (d < 0) d = -d;
  int l = a < b ? a : b;
  const double iT2 = 2500.0;
  const double iT4 = 6250000.0;
  double w = 0.0;
  if (d == 0) {
    w = 3.0;
    w += 2.0 * iT2 * (double)((a <= 98 ? 1 : 0) + (a >= 1 ? 1 : 0));
    double dd = (double)(((a - 2) >= 0 && (a - 2) <= 97) ? 1 : 0)
              + 4.0 * (double)(((a - 1) >= 0 && (a - 1) <= 97) ? 1 : 0)
              + (double)((a <= 97) ? 1 : 0);
    w += 2.0 * iT4 * dd;
  } else if (d == 1) {
    w = -2.0 * iT2;
    double dd = -2.0 * (double)(((l - 1) >= 0 && (l - 1) <= 97) ? 1 : 0)
                - 2.0 * (double)((l <= 97) ? 1 : 0);
    w += 2.0 * iT4 * dd;
  } else if (d == 2) {
    w = 2.0 * iT4 * (double)((l <= 97) ? 1 : 0);
  }
  return w;
}

__global__ __launch_bounds__(128) void qinv_kernel(double* __restrict__ cid,
                                                   float* __restrict__ QtT)
{
  __shared__ double Bb[100][4];
  __shared__ double Gb[100][4];
  __shared__ double invd[100];
  __shared__ double zl[100][52];   // 50-column batch of solves
  int tid = threadIdx.x;
  for (int q = tid; q < 400; q += 128) {
    int i = q >> 2, k = q & 3;
    int j = i - k;
    double v = 0.0;
    if (j >= 0) {
      v = Wfun(i, j) - Wfun(i + 1, j) - Wfun(i, j + 1) + Wfun(i + 1, j + 1);
      if (k == 0) v += 2.0 * 0.02 * 0.02;
    }
    Bb[i][k] = v;
  }
  __syncthreads();
  if (tid == 0) {                 // banded Cholesky B = G G'
    for (int i = 0; i < 100; ++i) {
      for (int k = 3; k >= 1; --k) {
        int j = i - k;
        if (j < 0) { Gb[i][k] = 0.0; continue; }
        double s = Bb[i][k];
        for (int m = k + 1; m <= 3; ++m)
          if (m <= i) s -= Gb[i][m] * Gb[j][m - k];
        Gb[i][k] = s * invd[j];
      }
      double s = Bb[i][0];
      for (int m = 1; m <= 3; ++m)
        if (m <= i) s -= Gb[i][m] * Gb[i][m];
      double g = sqrt(s);
      Gb[i][0] = g;
      invd[i] = 1.0 / g;
    }
  }
  __syncthreads();
  for (int bb = 0; bb < 2; ++bb) {
    if (tid < 50) {
      int c = bb * 50 + tid;
      double z0 = 0, z1 = 0, z2 = 0;
      for (int i = 0; i < 100; ++i) {           // forward: G z = D' e_c
        double v = (i == c ? 1.0 : 0.0) - (i == (c - 1) ? 1.0 : 0.0);
        double s = v - Gb[i][1] * z0 - Gb[i][2] * z1 - Gb[i][3] * z2;
        double z = s * invd[i];
        zl[i][tid] = z;
        z2 = z1; z1 = z0; z0 = z;
      }
      double y0 = 0, y1 = 0, y2 = 0;
      for (int i = 99; i >= 0; --i) {           // back: G' y = z
        double s = zl[i][tid];
        if (i + 1 <= 99) s -= Gb[i + 1][1] * y0;
        if (i + 2 <= 99) s -= Gb[i + 2][2] * y1;
        if (i + 3 <= 99) s -= Gb[i + 3][3] * y2;
        double y = s * invd[i];
        zl[i][tid] = y;
        y2 = y1; y1 = y0; y0 = y;
      }
      double ym = 0.0;
      for (int i = 0; i < 100; ++i) {           // x = D y (differences)
        double y = zl[i][tid];
        cid[i * 100 + c] = y - ym;
        ym = y;
      }
    }
    __syncthreads();
  }
  double invs = 1.0 / cid[0];
  for (int q = tid; q < 100 * 112; q += 128) {
    int i = q / 112, k = q - i * 112;
    double val = 0.0;
    if (k < 100)       val = cid[i * 100 + k] - cid[i * 100] * cid[k] * invs;
    else if (k == 100) val = cid[i * 100] * invs;
    QtT[q] = (float)val;
  }
}

// =====================================================================
// quantiles (unchanged)
// =====================================================================
__global__ __launch_bounds__(256) void quantile_kernel(const float* __restrict__ in,
                                                       float* __restrict__ med,
                                                       float* __restrict__ rinv)
{
  __shared__ float v[1024];
  int c = blockIdx.x, tid = threadIdx.x;
  for (int i = tid; i < 1024; i += 256) v[i] = in[i * NVARS + c];
  __syncthreads();
  for (int k = 2; k <= 1024; k <<= 1) {
    for (int j = k >> 1; j > 0; j >>= 1) {
      for (int i = tid; i < 1024; i += 256) {
        int ixj = i ^ j;
        if (ixj > i) {
          float a = v[i], b2 = v[ixj];
          bool up = ((i & k) == 0);
          if ((a > b2) == up) { v[i] = b2; v[ixj] = a; }
        }
      }
      __syncthreads();
    }
  }
  if (tid == 0) {
    float m  = v[511];
    float q1 = v[255] + 0.75f * (v[256] - v[255]);
    float q3 = v[767] + 0.25f * (v[768] - v[767]);
    float iq = q3 - q1;
    if (iq == 0.f) iq = 1.f;
    med[c] = m;
    rinv[c] = 1.f / iq;
  }
}

// ---- normalize + split to bf16 hi/lo, padded K=704 ----
__global__ __launch_bounds__(256) void normalize_split(const float* __restrict__ in,
                                                       const float* __restrict__ med,
                                                       const float* __restrict__ rinv,
                                                       ushort* __restrict__ Ah,
                                                       ushort* __restrict__ Al)
{
  int idx = blockIdx.x * 256 + threadIdx.x;
  if (idx >= 1024 * 704) return;
  int r = idx / 704, c = idx - r * 704;
  float v = 0.f;
  if (c < 700) v = (in[r * NVARS + c] - med[c]) * rinv[c];
  ushort h = f2bf(v);
  float fh = __uint_as_float(((unsigned)h) << 16);
  Ah[idx] = h;
  Al[idx] = f2bf(v - fh);
}

// ---- transpose + split: dst[n][k] = src[k][col0+n], zero padded ----
__global__ __launch_bounds__(256) void tsplit(const float* __restrict__ src,
                                              int srows, int scols, int sld, int col0,
                                              ushort* __restrict__ dh,
                                              ushort* __restrict__ dl, int dld)
{
  __shared__ float tile[32][33];
  int k0 = blockIdx.x * 32, n0 = blockIdx.y * 32;
  int tx = threadIdx.x, ty = threadIdx.y;   // (32, 8)
  for (int i = ty; i < 32; i += 8) {
    int k = k0 + i, c = col0 + n0 + tx;
    tile[i][tx] = (k < srows && c < scols) ? src[(size_t)k * sld + c] : 0.f;
  }
  __syncthreads();
  for (int i = ty; i < 32; i += 8) {
    int n = n0 + i, k = k0 + tx;
    float v = tile[tx][i];
    ushort h = f2bf(v);
    float fh = __uint_as_float(((unsigned)h) << 16);
    dh[(size_t)n * dld + k] = h;
    dl[(size_t)n * dld + k] = f2bf(v - fh);
  }
}

// =====================================================================
// MFMA GEMM, bf16 hi/lo split (3 products ~= f32 accuracy).
// =====================================================================
template <int BM, int BN, int MODE>
__global__ __launch_bounds__(256) void gemm_mfma(
    const ushort* __restrict__ Agh, const ushort* __restrict__ Agl,
    const ushort* __restrict__ Bgh, const ushort* __restrict__ Bgl,
    const float* __restrict__ bias, int bias_n,
    float* __restrict__ Cf, ushort* __restrict__ Chi, ushort* __restrict__ Clo,
    int Kp, int ldc)
{
  constexpr int ACH = BM * 4 / 256;
  constexpr int BCH = BN * 4 / 256;
  constexpr int MF = BM / 32;
  constexpr int NF = BN / 32;
  __shared__ __align__(16) ushort Ash[BM * 40];
  __shared__ __align__(16) ushort Asl[BM * 40];
  __shared__ __align__(16) ushort Bsh[BN * 40];
  __shared__ __align__(16) ushort Bsl[BN * 40];

  const int t = threadIdx.x;
  const size_t bm = (size_t)blockIdx.y * BM;
  const size_t bn = (size_t)blockIdx.x * BN;

  size_t aoff[ACH]; int awo[ACH];
#pragma unroll
  for (int s = 0; s < ACH; ++s) {
    int slot = t * ACH + s, row = slot >> 2, ch = slot & 3;
    aoff[s] = (bm + row) * (size_t)Kp + ch * 8;
    awo[s] = row * 40 + ch * 8;
  }
  size_t boff[BCH]; int bwo[BCH];
#pragma unroll
  for (int s = 0; s < BCH; ++s) {
    int slot = t * BCH + s, row = slot >> 2, ch = slot & 3;
    boff[s] = (bn + row) * (size_t)Kp + ch * 8;
    bwo[s] = row * 40 + ch * 8;
  }

  const int w = t >> 6, lane = t & 63;
  const int wr = w >> 1, wc = w & 1;
  const int fr = lane & 15, fg = lane >> 4;

  f32x4 acc[MF][NF];
#pragma unroll
  for (int a = 0; a < MF; ++a)
#pragma unroll
    for (int b = 0; b < NF; ++b) acc[a][b] = (f32x4){0.f, 0.f, 0.f, 0.f};

  const int nk = Kp >> 5;
  uint4 rAh[ACH], rAl[ACH], rBh[BCH], rBl[BCH];
#pragma unroll
  for (int s = 0; s < ACH; ++s) { rAh[s] = *(const uint4*)(Agh + aoff[s]); rAl[s] = *(const uint4*)(Agl + aoff[s]); }
#pragma unroll
  for (int s = 0; s < BCH; ++s) { rBh[s] = *(const uint4*)(Bgh + boff[s]); rBl[s] = *(const uint4*)(Bgl + boff[s]); }

  for (int kt = 0;; ++kt) {
    __syncthreads();
#pragma unroll
    for (int s = 0; s < ACH; ++s) { *(uint4*)&Ash[awo[s]] = rAh[s]; *(uint4*)&Asl[awo[s]] = rAl[s]; }
#pragma unroll
    for (int s = 0; s < BCH; ++s) { *(uint4*)&Bsh[bwo[s]] = rBh[s]; *(uint4*)&Bsl[bwo[s]] = rBl[s]; }
    __syncthreads();
    if (kt + 1 < nk) {
      int ko = (kt + 1) * 32;
#pragma unroll
      for (int s = 0; s < ACH; ++s) { rAh[s] = *(const uint4*)(Agh + aoff[s] + ko); rAl[s] = *(const uint4*)(Agl + aoff[s] + ko); }
#pragma unroll
      for (int s = 0; s < BCH; ++s) { rBh[s] = *(const uint4*)(Bgh + boff[s] + ko); rBl[s] = *(const uint4*)(Bgl + boff[s] + ko); }
    }
    bf16x8 fah[MF], fal[MF], fbh[NF], fbl[NF];
#pragma unroll
    for (int mf = 0; mf < MF; ++mf) {
      int off = (wr * (BM / 2) + mf * 16 + fr) * 40 + fg * 8;
      fah[mf] = *(const bf16x8*)&Ash[off];
      fal[mf] = *(const bf16x8*)&Asl[off];
    }
#pragma unroll
    for (int nf = 0; nf < NF; ++nf) {
      int off = (wc * (BN / 2) + nf * 16 + fr) * 40 + fg * 8;
      fbh[nf] = *(const bf16x8*)&Bsh[off];
      fbl[nf] = *(const bf16x8*)&Bsl[off];
    }
#pragma unroll
    for (int mf = 0; mf < MF; ++mf)
#pragma unroll
      for (int nf = 0; nf < NF; ++nf) {
        acc[mf][nf] = __builtin_amdgcn_mfma_f32_16x16x32_bf16(fah[mf], fbh[nf], acc[mf][nf], 0, 0, 0);
        acc[mf][nf] = __builtin_amdgcn_mfma_f32_16x16x32_bf16(fah[mf], fbl[nf], acc[mf][nf], 0, 0, 0);
        acc[mf][nf] = __builtin_amdgcn_mfma_f32_16x16x32_bf16(fal[mf], fbh[nf], acc[mf][nf], 0, 0, 0);
      }
    if (kt + 1 >= nk) break;
  }

#pragma unroll
  for (int mf = 0; mf < MF; ++mf)
#pragma unroll
    for (int nf = 0; nf < NF; ++nf) {
      int col = (int)bn + wc * (BN / 2) + nf * 16 + fr;
      int rowb = (int)bm + wr * (BM / 2) + mf * 16 + fg * 4;
#pragma unroll
      for (int j = 0; j < 4; ++j) {
        int row = rowb + j;
        float v = acc[mf][nf][j];
        if (MODE == 0) {
          float bv = (col < bias_n) ? bias[col] : 0.f;
          Cf[(size_t)row * ldc + col] = v + bv;
        } else {
          float r = fmaxf(v + bias[col], 0.f);
          ushort h = f2bf(r);
          float fh = __uint_as_float(((unsigned)h) << 16);
          Chi[(size_t)row * ldc + col] = h;
          Clo[(size_t)row * ldc + col] = f2bf(r - fh);
        }
      }
    }
}

// =====================================================================
// fallback path: f32 normalize + SIMT GEMM
// =====================================================================
__global__ __launch_bounds__(256) void normalize_kernel(const float* __restrict__ in,
                                                        const float* __restrict__ med,
                                                        const float* __restrict__ rinv,
                                                        float* __restrict__ An)
{
  int idx = blockIdx.x * 256 + threadIdx.x;
  if (idx < 1024 * NVARS) {
    int c = idx % NVARS;
    An[idx] = (in[idx] - med[c]) * rinv[c];
  }
}

template <bool RELU>
__global__ __launch_bounds__(256) void gemm_kernel(const float* __restrict__ A, int lda,
                                                   const float* __restrict__ B, int ldb,
                                                   const float* __restrict__ bias,
                                                   float* __restrict__ C, int ldc,
                                                   int N, int K)
{
  __shared__ __align__(16) float As[16][68];
  __shared__ __align__(16) float Bs[16][64];
  int tid = threadIdx.x;
  int bm = blockIdx.y * 64, bn = blockIdx.x * 64;
  int tx = tid & 15, ty = tid >> 4;
  float acc[4][4] = {};
  for (int k0 = 0; k0 < K; k0 += 16) {
    {
      int q = tid * 4;
      int m = q >> 4, kk = q & 15;
      const float* ap = A + (size_t)(bm + m) * lda + k0;
#pragma unroll
      for (int s2 = 0; s2 < 4; ++s2) {
        int kc = kk + s2;
        As[kc][m] = (k0 + kc < K) ? ap[kc] : 0.f;
      }
    }
#pragma unroll
    for (int s2 = 0; s2 < 4; ++s2) {
      int q = tid + s2 * 256;
      int kk = q >> 6, n = q & 63;
      float val = 0.f;
      if (k0 + kk < K && bn + n < N) val = B[(size_t)(k0 + kk) * ldb + bn + n];
      Bs[kk][n] = val;
    }
    __syncthreads();
#pragma unroll
    for (int kk = 0; kk < 16; ++kk) {
      float4 av = *reinterpret_cast<const float4*>(&As[kk][ty * 4]);
      float4 bv = *reinterpret_cast<const float4*>(&Bs[kk][tx * 4]);
      acc[0][0] += av.x * bv.x; acc[0][1] += av.x * bv.y; acc[0][2] += av.x * bv.z; acc[0][3] += av.x * bv.w;
      acc[1][0] += av.y * bv.x; acc[1][1] += av.y * bv.y; acc[1][2] += av.y * bv.z; acc[1][3] += av.y * bv.w;
      acc[2][0] += av.z * bv.x; acc[2][1] += av.z * bv.y; acc[2][2] += av.z * bv.z; acc[2][3] += av.z * bv.w;
      acc[3][0] += av.w * bv.x; acc[3][1] += av.w * bv.y; acc[3][2] += av.w * bv.z; acc[3][3] += av.w * bv.w;
    }
    __syncthreads();
  }
#pragma unroll
  for (int i = 0; i < 4; ++i) {
    int m = bm + ty * 4 + i;
#pragma unroll
    for (int j = 0; j < 4; ++j) {
      int n = bn + tx * 4 + j;
      if (n < N) {
        float r = acc[i][j] + bias[n];
        if (RELU) r = fmaxf(r, 0.f);
        C[(size_t)m * ldc + n] = r;
      }
    }
  }
}

// =====================================================================
// solver v5: v4 + QtT[100][112] transposed matvec (float4 Qt loads,
// uniform 28-k chunks, zero-padded tails).
// =====================================================================
__device__ __forceinline__ float rdlane(float v, int lane) {
  return __int_as_float(__builtin_amdgcn_readlane(__float_as_int(v), lane));
}

__device__ __forceinline__ float iscan(float v) {
  float f = v;
  int t;
  t = __builtin_amdgcn_update_dpp(0, __float_as_int(f), 0x111, 0xf, 0xf, false); // row_shr:1
  f += __int_as_float(t);
  t = __builtin_amdgcn_update_dpp(0, __float_as_int(f), 0x112, 0xf, 0xf, false); // row_shr:2
  f += __int_as_float(t);
  t = __builtin_amdgcn_update_dpp(0, __float_as_int(f), 0x114, 0xf, 0xf, false); // row_shr:4
  f += __int_as_float(t);
  t = __builtin_amdgcn_update_dpp(0, __float_as_int(f), 0x118, 0xf, 0xf, false); // row_shr:8
  f += __int_as_float(t);
  t = __builtin_amdgcn_update_dpp(0, __float_as_int(f), 0x142, 0xa, 0xf, false); // row_bcast:15
  f += __int_as_float(t);
  t = __builtin_amdgcn_update_dpp(0, __float_as_int(f), 0x143, 0xc, 0xf, false); // row_bcast:31
  f += __int_as_float(t);
  return f;
}

struct TR {
  float vp0, vm0, vp1, vm1;
  float ap0, am0, ap1, am1;
  float jp0, jm0, jp1, jm1;
  float pp0, pm0, pp1, pm1;
};

__device__ __forceinline__ void wpair(float tp, float tm, float& ws, float& wr) {
  float a = fmaxf(tp, 0.f), b = fmaxf(tm, 0.f);
  ws = b - a;
  wr = (tm - tp) - ws;
}

__device__ __forceinline__ void w_phase(const TR& t, int l, bool hi, float dth,
                                        float& os0, float& os1, float& or0, float& or1)
{
  float vs0, vr0, vs1, vr1, ys0, yr0, ys1, yr1;
  float zs0, zr0, zs1, zr1, ps0, pr0, ps1, pr1;
  wpair(t.vp0, t.vm0, vs0, vr0);
  wpair(t.ap0, t.am0, ys0, yr0);
  wpair(t.jp0, t.jm0, zs0, zr0);
  wpair(t.pp0, t.pm0, ps0, pr0);
  if (hi) { wpair(t.vp1, t.vm1, vs1, vr1); wpair(t.pp1, t.pm1, ps1, pr1); }
  else    { vs1 = vr1 = ps1 = pr1 = 0.f; }
  if (hi && l <= 34) { wpair(t.ap1, t.am1, ys1, yr1); } else { ys1 = yr1 = 0.f; }
  if (hi && l <= 33) { wpair(t.jp1, t.jm1, zs1, zr1); } else { zs1 = zr1 = 0.f; }

  const int lm1 = (l + 63) & 63, lm2 = (l + 62) & 63;
  float u1ys0 = __shfl(ys0, lm1), u1ys1 = __shfl(ys1, lm1);
  float u1zs0 = __shfl(zs0, lm1), u1zs1 = __shfl(zs1, lm1);
  float u2zs0 = __shfl(zs0, lm2), u2zs1 = __shfl(zs1, lm2);
  float u1yr0 = __shfl(yr0, lm1), u1yr1 = __shfl(yr1, lm1);
  float u1zr0 = __shfl(zr0, lm1), u1zr1 = __shfl(zr1, lm1);
  float u2zr0 = __shfl(zr0, lm2), u2zr1 = __shfl(zr1, lm2);

  float pa0s = ps0 + dth;
  float pa1s = hi ? ps1 + dth : 0.f;
  float pa0r = pr0;
  float pa1r = hi ? pr1 : 0.f;
  float s0s = iscan(pa0s);
  float s0r = iscan(pa0r);
  float tots = rdlane(s0s, 63), totr = rdlane(s0r, 63);
  float s1s = iscan(pa1s) + tots;
  float s1r = iscan(pa1r) + totr;
  float Ss = rdlane(s1s, 35), Sr = rdlane(s1r, 35);
  float rc0s = Ss - s0s + pa0s, rc1s = Ss - s1s + pa1s;
  float rc0r = Sr - s0r + pa0r, rc1r = Sr - s1r + pa1r;

  float ym1s0 = l ? u1ys0 : 0.f, zm1s0 = l ? u1zs0 : 0.f, zm2s0 = (l >= 2) ? u2zs0 : 0.f;
  float ym1r0 = l ? u1yr0 : 0.f, zm1r0 = l ? u1zr0 : 0.f, zm2r0 = (l >= 2) ? u2zr0 : 0.f;
  os0 = vs0 + 50.f * (ym1s0 - ys0) + 2500.f * (zm2s0 - 2.f * zm1s0 + zs0) + 0.02f * rc0s;
  or0 = vr0 + 50.f * (ym1r0 - yr0) + 2500.f * (zm2r0 - 2.f * zm1r0 + zr0) + 0.02f * rc0r;
  float ym1s1 = l ? u1ys1 : u1ys0, zm1s1 = l ? u1zs1 : u1zs0, zm2s1 = (l >= 2) ? u2zs1 : u2zs0;
  float ym1r1 = l ? u1yr1 : u1yr0, zm1r1 = l ? u1zr1 : u1zr0, zm2r1 = (l >= 2) ? u2zr1 : u2zr0;
  os1 = vs1 + 50.f * (ym1s1 - ys1) + 2500.f * (zm2s1 - 2.f * zm1s1 + zs1) + 0.02f * rc1s;
  or1 = vr1 + 50.f * (ym1r1 - yr1) + 2500.f * (zm2r1 - 2.f * zm1r1 + zr1) + 0.02f * rc1r;
}

__global__ __launch_bounds__(448, 4) void solver_kernel(const float* __restrict__ out2,
                                                        const float* __restrict__ input,
                                                        const float* __restrict__ theta,
                                                        const float* __restrict__ vstart,
                                                        const float* __restrict__ QtT,
                                                        float* __restrict__ out, int ldo)
{
  __shared__ __align__(16) float ru_t[112][12];   // rows 101..111 zeroed
  __shared__ float pm[4][700];
  __shared__ float part[7][20][3];
  __shared__ float prfp[40];

  const int b = blockIdx.x, tid = threadIdx.x;
  const int d = tid >> 6, l = tid & 63;
  const bool hi = (l < 36);
  const int i2 = 64 + l;
  const float th = theta[b];
  const float dth = (d == 3) ? -2.f * th : 0.f;
  const float bp  = (d <= 3) ? (3.14f - th) : (3.14f + th);
  const float bm2 = (d <  3) ? (3.14f - th) : (3.14f + th);
  const float* orow = out2 + (size_t)b * ldo;
  const float* srow = orow + 700;

  float lam0 = orow[d * 100 + l];
  float xs0  = input[(size_t)b * NVARS + d * 100 + l];
  float lam1 = hi ? orow[d * 100 + i2] : 0.f;
  float xs1  = hi ? input[(size_t)b * NVARS + d * 100 + i2] : 0.f;

  TR t;
  {
    const int vb = d * 200, ab = 1400 + d * 198, jb = 2786 + d * 196, pb = 4158 + d * 200;
    t.vp0 = fmaxf(srow[vb + l], 0.f);        t.vm0 = fmaxf(srow[vb + 100 + l], 0.f);
    t.ap0 = fmaxf(srow[ab + l], 0.f);        t.am0 = fmaxf(srow[ab + 99 + l], 0.f);
    t.jp0 = fmaxf(srow[jb + l], 0.f);        t.jm0 = fmaxf(srow[jb + 98 + l], 0.f);
    t.pp0 = fmaxf(srow[pb + l], 0.f);        t.pm0 = fmaxf(srow[pb + 100 + l], 0.f);
    t.vp1 = hi        ? fmaxf(srow[vb + i2], 0.f)      : 0.f;
    t.vm1 = hi        ? fmaxf(srow[vb + 100 + i2], 0.f) : 0.f;
    t.ap1 = (l <= 34) ? fmaxf(srow[ab + i2], 0.f)      : 0.f;
    t.am1 = (l <= 34) ? fmaxf(srow[ab + 99 + i2], 0.f) : 0.f;
    t.jp1 = (l <= 33) ? fmaxf(srow[jb + i2], 0.f)      : 0.f;
    t.jm1 = (l <= 33) ? fmaxf(srow[jb + 98 + i2], 0.f) : 0.f;
    t.pp1 = hi        ? fmaxf(srow[pb + i2], 0.f)      : 0.f;
    t.pm1 = hi        ? fmaxf(srow[pb + 100 + i2], 0.f) : 0.f;
  }
  if (l == 0) ru_t[100][d] = vstart[b * 7 + d];
  for (int q = tid; q < 132; q += 448) ru_t[101 + q / 12][q % 12] = 0.f;  // pad rows

  // pre-loop: ru from s0
  {
    float os0, os1, or0, or1;
    w_phase(t, l, hi, dth, os0, os1, or0, or1);
    ru_t[l][d] = lam0 + xs0 + os0;
    if (hi) ru_t[i2][d] = lam1 + xs1 + os1;
  }

  for (int it = 0; it < MAXIT; ++it) {
    __syncthreads();   // barrier 1: ru ready
    // ---- phase B: xi partials, QtT float4 loads, uniform 28-k chunks ----
    {
      int kc = tid / 112, r = tid - kc * 112;
      if (r < 100) {
        const int k0 = kc * 28;
        float4 qv[7];
#pragma unroll
        for (int j = 0; j < 7; ++j)
          qv[j] = *reinterpret_cast<const float4*>(&QtT[r * 112 + k0 + j * 4]);
        float acc[7] = {0.f, 0.f, 0.f, 0.f, 0.f, 0.f, 0.f};
        const float* qs = reinterpret_cast<const float*>(qv);
#pragma unroll
        for (int jj = 0; jj < 28; ++jj) {
          float q = qs[jj];
          float4 ra = *reinterpret_cast<const float4*>(&ru_t[k0 + jj][0]);
          float4 rb = *reinterpret_cast<const float4*>(&ru_t[k0 + jj][4]);
          acc[0] += q * ra.x; acc[1] += q * ra.y; acc[2] += q * ra.z; acc[3] += q * ra.w;
          acc[4] += q * rb.x; acc[5] += q * rb.y; acc[6] += q * rb.z;
        }
#pragma unroll
        for (int dd = 0; dd < 7; ++dd) pm[kc][dd * 100 + r] = acc[dd];
      }
    }
    __syncthreads();   // barrier 2: partials ready

    // ---- phase C: fold partials -> xi; t = b - A xi (regs); r2, ds2 ----
    float r2 = 0.f, ds2 = 0.f, dl2 = 0.f;
    {
      const int a0 = d * 100 + l;
      float x0 = pm[0][a0] + pm[1][a0] + pm[2][a0] + pm[3][a0];
      float x1 = 0.f;
      if (hi) {
        const int a1 = d * 100 + i2;
        x1 = pm[0][a1] + pm[1][a1] + pm[2][a1] + pm[3][a1];
      }
      const int lp1 = (l + 1) & 63, lp2 = (l + 2) & 63;
      float d1x0 = __shfl(x0, lp1), d1x1 = __shfl(x1, lp1);
      float d2x0 = __shfl(x0, lp2), d2x1 = __shfl(x1, lp2);
      float xp1_0 = (l == 63) ? d1x1 : d1x0;
      float xp2_0 = (l >= 62) ? d2x1 : d2x0;
      float xp1_1 = d1x1, xp2_1 = d2x1;
      float c0 = iscan(x0);
      float tt = rdlane(c0, 63);
      float c1 = iscan(hi ? x1 : 0.f) + tt;
#define NU(tp_, tm_, np_, nm_) { \
      float sop = fmaxf(tp_, 0.f), som = fmaxf(tm_, 0.f); \
      float snp = fmaxf(np_, 0.f), snm = fmaxf(nm_, 0.f); \
      float e1 = sop - snp, e2 = som - snm; ds2 += e1 * e1 + e2 * e2; \
      float q1 = snp - (np_), q2 = snm - (nm_); r2 += q1 * q1 + q2 * q2; \
      tp_ = np_; tm_ = nm_; }
      { float np = 1.f - x0, nm = 1.f + x0; NU(t.vp0, t.vm0, np, nm) }
      { float a = 50.f * (xp1_0 - x0); float np = 2.f - a, nm = 2.f + a; NU(t.ap0, t.am0, np, nm) }
      { float j = 2500.f * (xp2_0 - 2.f * xp1_0 + x0); float np = 5.f - j, nm = 5.f + j; NU(t.jp0, t.jm0, np, nm) }
      { float np = bp - 0.02f * c0, nm = bm2 + 0.02f * c0; NU(t.pp0, t.pm0, np, nm) }
      if (hi) {
        { float np = 1.f - x1, nm = 1.f + x1; NU(t.vp1, t.vm1, np, nm) }
        { float np = bp - 0.02f * c1, nm = bm2 + 0.02f * c1; NU(t.pp1, t.pm1, np, nm) }
      }
      if (l <= 34) { float a = 50.f * (xp1_1 - x1); float np = 2.f - a, nm = 2.f + a; NU(t.ap1, t.am1, np, nm) }
      if (l <= 33) { float j = 2500.f * (xp2_1 - 2.f * xp1_1 + x1); float np = 5.f - j, nm = 5.f + j; NU(t.jp1, t.jm1, np, nm) }
#undef NU
    }

    // ---- merged phase W: lam -= g, then ru for next iter ----
    {
      float os0, os1, or0, or1;
      w_phase(t, l, hi, dth, os0, os1, or0, or1);
      lam0 -= or0; dl2 += or0 * or0;
      ru_t[l][d] = lam0 + xs0 + os0;
      if (hi) {
        lam1 -= or1; dl2 += or1 * or1;
        ru_t[i2][d] = lam1 + xs1 + os1;
      }
    }

    r2 = iscan(r2); ds2 = iscan(ds2); dl2 = iscan(dl2);
    if (l == 63) { part[d][it][0] = r2; part[d][it][1] = ds2; part[d][it][2] = dl2; }
  }

  __syncthreads();
  {
    const int a0 = d * 100 + l;
    float x0 = pm[0][a0] + pm[1][a0] + pm[2][a0] + pm[3][a0];
    float* xout = out + (size_t)b * NVARS + d * 100;
    xout[l] = x0;
    if (hi) {
      const int a1 = d * 100 + i2;
      xout[i2] = pm[0][a1] + pm[1][a1] + pm[2][a1] + pm[3][a1];
    }
  }
  if (tid < 20) {
    int it = tid;
    float R2 = 0.f, DS2 = 0.f, DL2 = 0.f;
    for (int dd = 0; dd < 7; ++dd) {
      R2 += part[dd][it][0]; DS2 += part[dd][it][1]; DL2 += part[dd][it][2];
    }
    float pr = sqrtf(R2), fp = sqrtf(DL2) + sqrtf(DS2);
    out[718848 + it * 1024 + b] = pr;
    out[739328 + it * 1024 + b] = fp;
    prfp[it] = pr; prfp[20 + it] = fp;
  }
  __syncthreads();
  if (tid == 0) {
    float ap = 0.f, af = 0.f;
    for (int it = 0; it < 20; ++it) { ap += prfp[it]; af += prfp[20 + it]; }
    out[716800 + b] = af / 20.f;
    out[717824 + b] = ap / 20.f;
  }
}

// =====================================================================
extern "C" void kernel_launch(void* const* d_in, const int* in_sizes, int n_in,
                              void* d_out, int out_size, void* d_ws, size_t ws_size,
                              hipStream_t stream) {
  (void)in_sizes; (void)n_in; (void)out_size;
  const float* input  = (const float*)d_in[0];
  const float* theta  = (const float*)d_in[1];
  const float* vstart = (const float*)d_in[2];
  const float* W1     = (const float*)d_in[3];
  const float* b1     = (const float*)d_in[4];
  const float* W2     = (const float*)d_in[5];
  const float* b2     = (const float*)d_in[6];
  float* out = (float*)d_out;

  float* wsf  = (float*)d_ws;
  double* cid = (double*)d_ws;         // 10000 f64 = 20000 slots
  float* QtT  = wsf + 20000;           // 100*112
  float* med  = wsf + 31200;           // 700
  float* rinv = wsf + 31900;           // 700

  hipLaunchKernelGGL(qinv_kernel, dim3(1), dim3(128), 0, stream, cid, QtT);
  hipLaunchKernelGGL(quantile_kernel, dim3(700), dim3(256), 0, stream, input, med, rinv);

  const size_t HHI = 32600, HLO = 556888, W2TH = 1081176, W2TL = 4292440,
               OUT2 = 7503704, NEED = 13926232;
  const size_t ANH = OUT2, ANL = OUT2 + 360448, W1TH = OUT2 + 720896, W1TL = OUT2 + 1081344;

  if (ws_size >= NEED * 4ull) {
    ushort* an_h  = (ushort*)(wsf + ANH);
    ushort* an_l  = (ushort*)(wsf + ANL);
    ushort* w1t_h = (ushort*)(wsf + W1TH);
    ushort* w1t_l = (ushort*)(wsf + W1TL);
    ushort* h_h   = (ushort*)(wsf + HHI);
    ushort* h_l   = (ushort*)(wsf + HLO);
    ushort* w2t_h = (ushort*)(wsf + W2TH);
    ushort* w2t_l = (ushort*)(wsf + W2TL);
    float*  out2  = wsf + OUT2;

    hipLaunchKernelGGL(normalize_split, dim3((1024 * 704 + 255) / 256), dim3(256), 0, stream,
                       input, med, rinv, an_h, an_l);
    hipLaunchKernelGGL(tsplit, dim3(22, 32), dim3(32, 8), 0, stream,
                       W1, 700, 1024, 1024, 0, w1t_h, w1t_l, 704);
    hipLaunchKernelGGL(tsplit, dim3(32, 196), dim3(32, 8), 0, stream,
                       W2, 1024, 6958, 6958, 700, w2t_h, w2t_l, 1024);
    hipLaunchKernelGGL((gemm_mfma<64, 64, 1>), dim3(16, 16), dim3(256), 0, stream,
                       an_h, an_l, w1t_h, w1t_l, b1, 1024,
                       (float*)nullptr, h_h, h_l, 704, 1024);
    hipLaunchKernelGGL((gemm_mfma<64, 128, 0>), dim3(49, 16), dim3(256), 0, stream,
                       h_h, h_l, w2t_h, w2t_l, b2 + 700, 6258,
                       out2, (ushort*)nullptr, (ushort*)nullptr, 1024, 6272);
    hipLaunchKernelGGL(solver_kernel, dim3(1024), dim3(448), 0, stream,
                       out2, input, theta, vstart, QtT, out, 6272);
  } else {
    float* An   = wsf + 32600;
    float* h    = wsf + 749400;
    float* out2 = wsf + 1797976;
    if (ws_size < (size_t)(1797976 + 6408192) * 4) return;
    hipLaunchKernelGGL(normalize_kernel, dim3(2800), dim3(256), 0, stream, input, med, rinv, An);
    hipLaunchKernelGGL((gemm_kernel<true>), dim3(16, 16), dim3(256), 0, stream,
                       An, NVARS, W1, 1024, b1, h, 1024, 1024, NVARS);
    hipLaunchKernelGGL((gemm_kernel<false>), dim3(98, 16), dim3(256), 0, stream,
                       h, 1024, W2 + 700, 6958, b2 + 700, out2, 6258, 6258, 1024);
    hipLaunchKernelGGL(solver_kernel, dim3(1024), dim3(448), 0, stream,
                       out2, input, theta, vstart, QtT, out, 6258);
  }
}

// Round 8
// 566.877 us; speedup vs baseline: 1.2208x; 1.1353x over previous
//
#include <hip/hip_runtime.h>

// ---------------- problem constants ----------------
#define NVARS 700
#define MC    5558
#define MAXIT 20

typedef __attribute__((ext_vector_type(8))) short bf16x8;
typedef __attribute__((ext_vector_type(4))) float f32x4;

__device__ __forceinline__ ushort f2bf(float x) {
  unsigned u = __float_as_uint(x);
  return (ushort)((u + 0x7FFFu + ((u >> 16) & 1u)) >> 16);
}

// =====================================================================
// qinv v2: LDS-resident triangular solves.
// Outputs QtT[i*112 + k] = Qd_inv_top[i][k] (k<=100; 101..111 zero pad).
// =====================================================================
__device__ __forceinline__ double Wfun(int a, int b) {
  if (a < 0 || a > 99 || b < 0 || b > 99) return 0.0;
  int d = a - b; if (d < 0) d = -d;
  int l = a < b ? a : b;
  const double iT2 = 2500.0;
  const double iT4 = 6250000.0;
  double w = 0.0;
  if (d == 0) {
    w = 3.0;
    w += 2.0 * iT2 * (double)((a <= 98 ? 1 : 0) + (a >= 1 ? 1 : 0));
    double dd = (double)(((a - 2) >= 0 && (a - 2) <= 97) ? 1 : 0)
              + 4.0 * (double)(((a - 1) >= 0 && (a - 1) <= 97) ? 1 : 0)
              + (double)((a <= 97) ? 1 : 0);
    w += 2.0 * iT4 * dd;
  } else if (d == 1) {
    w = -2.0 * iT2;
    double dd = -2.0 * (double)(((l - 1) >= 0 && (l - 1) <= 97) ? 1 : 0)
                - 2.0 * (double)((l <= 97) ? 1 : 0);
    w += 2.0 * iT4 * dd;
  } else if (d == 2) {
    w = 2.0 * iT4 * (double)((l <= 97) ? 1 : 0);
  }
  return w;
}

__global__ __launch_bounds__(128) void qinv_kernel(double* __restrict__ cid,
                                                   float* __restrict__ QtT)
{
  __shared__ double Bb[100][4];
  __shared__ double Gb[100][4];
  __shared__ double invd[100];
  __shared__ double zl[100][52];
  int tid = threadIdx.x;
  for (int q = tid; q < 400; q += 128) {
    int i = q >> 2, k = q & 3;
    int j = i - k;
    double v = 0.0;
    if (j >= 0) {
      v = Wfun(i, j) - Wfun(i + 1, j) - Wfun(i, j + 1) + Wfun(i + 1, j + 1);
      if (k == 0) v += 2.0 * 0.02 * 0.02;
    }
    Bb[i][k] = v;
  }
  __syncthreads();
  if (tid == 0) {
    for (int i = 0; i < 100; ++i) {
      for (int k = 3; k >= 1; --k) {
        int j = i - k;
        if (j < 0) { Gb[i][k] = 0.0; continue; }
        double s = Bb[i][k];
        for (int m = k + 1; m <= 3; ++m)
          if (m <= i) s -= Gb[i][m] * Gb[j][m - k];
        Gb[i][k] = s * invd[j];
      }
      double s = Bb[i][0];
      for (int m = 1; m <= 3; ++m)
        if (m <= i) s -= Gb[i][m] * Gb[i][m];
      double g = sqrt(s);
      Gb[i][0] = g;
      invd[i] = 1.0 / g;
    }
  }
  __syncthreads();
  for (int bb = 0; bb < 2; ++bb) {
    if (tid < 50) {
      int c = bb * 50 + tid;
      double z0 = 0, z1 = 0, z2 = 0;
      for (int i = 0; i < 100; ++i) {
        double v = (i == c ? 1.0 : 0.0) - (i == (c - 1) ? 1.0 : 0.0);
        double s = v - Gb[i][1] * z0 - Gb[i][2] * z1 - Gb[i][3] * z2;
        double z = s * invd[i];
        zl[i][tid] = z;
        z2 = z1; z1 = z0; z0 = z;
      }
      double y0 = 0, y1 = 0, y2 = 0;
      for (int i = 99; i >= 0; --i) {
        double s = zl[i][tid];
        if (i + 1 <= 99) s -= Gb[i + 1][1] * y0;
        if (i + 2 <= 99) s -= Gb[i + 2][2] * y1;
        if (i + 3 <= 99) s -= Gb[i + 3][3] * y2;
        double y = s * invd[i];
        zl[i][tid] = y;
        y2 = y1; y1 = y0; y0 = y;
      }
      double ym = 0.0;
      for (int i = 0; i < 100; ++i) {
        double y = zl[i][tid];
        cid[i * 100 + c] = y - ym;
        ym = y;
      }
    }
    __syncthreads();
  }
  double invs = 1.0 / cid[0];
  for (int q = tid; q < 100 * 112; q += 128) {
    int i = q / 112, k = q - i * 112;
    double val = 0.0;
    if (k < 100)       val = cid[i * 100 + k] - cid[i * 100] * cid[k] * invs;
    else if (k == 100) val = cid[i * 100] * invs;
    QtT[q] = (float)val;
  }
}

// =====================================================================
// quantiles (unchanged)
// =====================================================================
__global__ __launch_bounds__(256) void quantile_kernel(const float* __restrict__ in,
                                                       float* __restrict__ med,
                                                       float* __restrict__ rinv)
{
  __shared__ float v[1024];
  int c = blockIdx.x, tid = threadIdx.x;
  for (int i = tid; i < 1024; i += 256) v[i] = in[i * NVARS + c];
  __syncthreads();
  for (int k = 2; k <= 1024; k <<= 1) {
    for (int j = k >> 1; j > 0; j >>= 1) {
      for (int i = tid; i < 1024; i += 256) {
        int ixj = i ^ j;
        if (ixj > i) {
          float a = v[i], b2 = v[ixj];
          bool up = ((i & k) == 0);
          if ((a > b2) == up) { v[i] = b2; v[ixj] = a; }
        }
      }
      __syncthreads();
    }
  }
  if (tid == 0) {
    float m  = v[511];
    float q1 = v[255] + 0.75f * (v[256] - v[255]);
    float q3 = v[767] + 0.25f * (v[768] - v[767]);
    float iq = q3 - q1;
    if (iq == 0.f) iq = 1.f;
    med[c] = m;
    rinv[c] = 1.f / iq;
  }
}

// ---- normalize + split to bf16 hi/lo, padded K=704 ----
__global__ __launch_bounds__(256) void normalize_split(const float* __restrict__ in,
                                                       const float* __restrict__ med,
                                                       const float* __restrict__ rinv,
                                                       ushort* __restrict__ Ah,
                                                       ushort* __restrict__ Al)
{
  int idx = blockIdx.x * 256 + threadIdx.x;
  if (idx >= 1024 * 704) return;
  int r = idx / 704, c = idx - r * 704;
  float v = 0.f;
  if (c < 700) v = (in[r * NVARS + c] - med[c]) * rinv[c];
  ushort h = f2bf(v);
  float fh = __uint_as_float(((unsigned)h) << 16);
  Ah[idx] = h;
  Al[idx] = f2bf(v - fh);
}

// ---- transpose + split: dst[n][k] = src[k][col0+n], zero padded ----
__global__ __launch_bounds__(256) void tsplit(const float* __restrict__ src,
                                              int srows, int scols, int sld, int col0,
                                              ushort* __restrict__ dh,
                                              ushort* __restrict__ dl, int dld)
{
  __shared__ float tile[32][33];
  int k0 = blockIdx.x * 32, n0 = blockIdx.y * 32;
  int tx = threadIdx.x, ty = threadIdx.y;   // (32, 8)
  for (int i = ty; i < 32; i += 8) {
    int k = k0 + i, c = col0 + n0 + tx;
    tile[i][tx] = (k < srows && c < scols) ? src[(size_t)k * sld + c] : 0.f;
  }
  __syncthreads();
  for (int i = ty; i < 32; i += 8) {
    int n = n0 + i, k = k0 + tx;
    float v = tile[tx][i];
    ushort h = f2bf(v);
    float fh = __uint_as_float(((unsigned)h) << 16);
    dh[(size_t)n * dld + k] = h;
    dl[(size_t)n * dld + k] = f2bf(v - fh);
  }
}

// =====================================================================
// MFMA GEMM, bf16 hi/lo split. XCD-aware bijective block swizzle:
// 1D grid (multiple of 8); wg -> gid = (wg&7)*chunk + (wg>>3); bx-major.
// Each XCD owns a contiguous chunk of bx (B panels) -> per-XCD L2
// footprint ~B/8 + A instead of the whole B matrix (R7: 571MB fetch).
// =====================================================================
template <int BM, int BN, int MODE>
__global__ __launch_bounds__(256) void gemm_mfma(
    const ushort* __restrict__ Agh, const ushort* __restrict__ Agl,
    const ushort* __restrict__ Bgh, const ushort* __restrict__ Bgl,
    const float* __restrict__ bias, int bias_n,
    float* __restrict__ Cf, ushort* __restrict__ Chi, ushort* __restrict__ Clo,
    int Kp, int ldc, int nby, int chunk)
{
  constexpr int ACH = BM * 4 / 256;
  constexpr int BCH = BN * 4 / 256;
  constexpr int MF = BM / 32;
  constexpr int NF = BN / 32;
  __shared__ __align__(16) ushort Ash[BM * 40];
  __shared__ __align__(16) ushort Asl[BM * 40];
  __shared__ __align__(16) ushort Bsh[BN * 40];
  __shared__ __align__(16) ushort Bsl[BN * 40];

  const int t = threadIdx.x;
  const int wg = blockIdx.x;
  const int gid = (wg & 7) * chunk + (wg >> 3);
  const int bxi = gid / nby, byi = gid - bxi * nby;
  const size_t bm = (size_t)byi * BM;
  const size_t bn = (size_t)bxi * BN;

  size_t aoff[ACH]; int awo[ACH];
#pragma unroll
  for (int s = 0; s < ACH; ++s) {
    int slot = t * ACH + s, row = slot >> 2, ch = slot & 3;
    aoff[s] = (bm + row) * (size_t)Kp + ch * 8;
    awo[s] = row * 40 + ch * 8;
  }
  size_t boff[BCH]; int bwo[BCH];
#pragma unroll
  for (int s = 0; s < BCH; ++s) {
    int slot = t * BCH + s, row = slot >> 2, ch = slot & 3;
    boff[s] = (bn + row) * (size_t)Kp + ch * 8;
    bwo[s] = row * 40 + ch * 8;
  }

  const int w = t >> 6, lane = t & 63;
  const int wr = w >> 1, wc = w & 1;
  const int fr = lane & 15, fg = lane >> 4;

  f32x4 acc[MF][NF];
#pragma unroll
  for (int a = 0; a < MF; ++a)
#pragma unroll
    for (int b = 0; b < NF; ++b) acc[a][b] = (f32x4){0.f, 0.f, 0.f, 0.f};

  const int nk = Kp >> 5;
  uint4 rAh[ACH], rAl[ACH], rBh[BCH], rBl[BCH];
#pragma unroll
  for (int s = 0; s < ACH; ++s) { rAh[s] = *(const uint4*)(Agh + aoff[s]); rAl[s] = *(const uint4*)(Agl + aoff[s]); }
#pragma unroll
  for (int s = 0; s < BCH; ++s) { rBh[s] = *(const uint4*)(Bgh + boff[s]); rBl[s] = *(const uint4*)(Bgl + boff[s]); }

  for (int kt = 0;; ++kt) {
    __syncthreads();
#pragma unroll
    for (int s = 0; s < ACH; ++s) { *(uint4*)&Ash[awo[s]] = rAh[s]; *(uint4*)&Asl[awo[s]] = rAl[s]; }
#pragma unroll
    for (int s = 0; s < BCH; ++s) { *(uint4*)&Bsh[bwo[s]] = rBh[s]; *(uint4*)&Bsl[bwo[s]] = rBl[s]; }
    __syncthreads();
    if (kt + 1 < nk) {
      int ko = (kt + 1) * 32;
#pragma unroll
      for (int s = 0; s < ACH; ++s) { rAh[s] = *(const uint4*)(Agh + aoff[s] + ko); rAl[s] = *(const uint4*)(Agl + aoff[s] + ko); }
#pragma unroll
      for (int s = 0; s < BCH; ++s) { rBh[s] = *(const uint4*)(Bgh + boff[s] + ko); rBl[s] = *(const uint4*)(Bgl + boff[s] + ko); }
    }
    bf16x8 fah[MF], fal[MF], fbh[NF], fbl[NF];
#pragma unroll
    for (int mf = 0; mf < MF; ++mf) {
      int off = (wr * (BM / 2) + mf * 16 + fr) * 40 + fg * 8;
      fah[mf] = *(const bf16x8*)&Ash[off];
      fal[mf] = *(const bf16x8*)&Asl[off];
    }
#pragma unroll
    for (int nf = 0; nf < NF; ++nf) {
      int off = (wc * (BN / 2) + nf * 16 + fr) * 40 + fg * 8;
      fbh[nf] = *(const bf16x8*)&Bsh[off];
      fbl[nf] = *(const bf16x8*)&Bsl[off];
    }
#pragma unroll
    for (int mf = 0; mf < MF; ++mf)
#pragma unroll
      for (int nf = 0; nf < NF; ++nf) {
        acc[mf][nf] = __builtin_amdgcn_mfma_f32_16x16x32_bf16(fah[mf], fbh[nf], acc[mf][nf], 0, 0, 0);
        acc[mf][nf] = __builtin_amdgcn_mfma_f32_16x16x32_bf16(fah[mf], fbl[nf], acc[mf][nf], 0, 0, 0);
        acc[mf][nf] = __builtin_amdgcn_mfma_f32_16x16x32_bf16(fal[mf], fbh[nf], acc[mf][nf], 0, 0, 0);
      }
    if (kt + 1 >= nk) break;
  }

#pragma unroll
  for (int mf = 0; mf < MF; ++mf)
#pragma unroll
    for (int nf = 0; nf < NF; ++nf) {
      int col = (int)bn + wc * (BN / 2) + nf * 16 + fr;
      int rowb = (int)bm + wr * (BM / 2) + mf * 16 + fg * 4;
#pragma unroll
      for (int j = 0; j < 4; ++j) {
        int row = rowb + j;
        float v = acc[mf][nf][j];
        if (MODE == 0) {
          float bv = (col < bias_n) ? bias[col] : 0.f;
          Cf[(size_t)row * ldc + col] = v + bv;
        } else {
          float r = fmaxf(v + bias[col], 0.f);
          ushort h = f2bf(r);
          float fh = __uint_as_float(((unsigned)h) << 16);
          Chi[(size_t)row * ldc + col] = h;
          Clo[(size_t)row * ldc + col] = f2bf(r - fh);
        }
      }
    }
}

// =====================================================================
// fallback path: f32 normalize + SIMT GEMM
// =====================================================================
__global__ __launch_bounds__(256) void normalize_kernel(const float* __restrict__ in,
                                                        const float* __restrict__ med,
                                                        const float* __restrict__ rinv,
                                                        float* __restrict__ An)
{
  int idx = blockIdx.x * 256 + threadIdx.x;
  if (idx < 1024 * NVARS) {
    int c = idx % NVARS;
    An[idx] = (in[idx] - med[c]) * rinv[c];
  }
}

template <bool RELU>
__global__ __launch_bounds__(256) void gemm_kernel(const float* __restrict__ A, int lda,
                                                   const float* __restrict__ B, int ldb,
                                                   const float* __restrict__ bias,
                                                   float* __restrict__ C, int ldc,
                                                   int N, int K)
{
  __shared__ __align__(16) float As[16][68];
  __shared__ __align__(16) float Bs[16][64];
  int tid = threadIdx.x;
  int bm = blockIdx.y * 64, bn = blockIdx.x * 64;
  int tx = tid & 15, ty = tid >> 4;
  float acc[4][4] = {};
  for (int k0 = 0; k0 < K; k0 += 16) {
    {
      int q = tid * 4;
      int m = q >> 4, kk = q & 15;
      const float* ap = A + (size_t)(bm + m) * lda + k0;
#pragma unroll
      for (int s2 = 0; s2 < 4; ++s2) {
        int kc = kk + s2;
        As[kc][m] = (k0 + kc < K) ? ap[kc] : 0.f;
      }
    }
#pragma unroll
    for (int s2 = 0; s2 < 4; ++s2) {
      int q = tid + s2 * 256;
      int kk = q >> 6, n = q & 63;
      float val = 0.f;
      if (k0 + kk < K && bn + n < N) val = B[(size_t)(k0 + kk) * ldb + bn + n];
      Bs[kk][n] = val;
    }
    __syncthreads();
#pragma unroll
    for (int kk = 0; kk < 16; ++kk) {
      float4 av = *reinterpret_cast<const float4*>(&As[kk][ty * 4]);
      float4 bv = *reinterpret_cast<const float4*>(&Bs[kk][tx * 4]);
      acc[0][0] += av.x * bv.x; acc[0][1] += av.x * bv.y; acc[0][2] += av.x * bv.z; acc[0][3] += av.x * bv.w;
      acc[1][0] += av.y * bv.x; acc[1][1] += av.y * bv.y; acc[1][2] += av.y * bv.z; acc[1][3] += av.y * bv.w;
      acc[2][0] += av.z * bv.x; acc[2][1] += av.z * bv.y; acc[2][2] += av.z * bv.z; acc[2][3] += av.z * bv.w;
      acc[3][0] += av.w * bv.x; acc[3][1] += av.w * bv.y; acc[3][2] += av.w * bv.z; acc[3][3] += av.w * bv.w;
    }
    __syncthreads();
  }
#pragma unroll
  for (int i = 0; i < 4; ++i) {
    int m = bm + ty * 4 + i;
#pragma unroll
    for (int j = 0; j < 4; ++j) {
      int n = bn + tx * 4 + j;
      if (n < N) {
        float r = acc[i][j] + bias[n];
        if (RELU) r = fmaxf(r, 0.f);
        C[(size_t)m * ldc + n] = r;
      }
    }
  }
}

// =====================================================================
// solver v5 (unchanged from R7)
// =====================================================================
__device__ __forceinline__ float rdlane(float v, int lane) {
  return __int_as_float(__builtin_amdgcn_readlane(__float_as_int(v), lane));
}

__device__ __forceinline__ float iscan(float v) {
  float f = v;
  int t;
  t = __builtin_amdgcn_update_dpp(0, __float_as_int(f), 0x111, 0xf, 0xf, false); // row_shr:1
  f += __int_as_float(t);
  t = __builtin_amdgcn_update_dpp(0, __float_as_int(f), 0x112, 0xf, 0xf, false); // row_shr:2
  f += __int_as_float(t);
  t = __builtin_amdgcn_update_dpp(0, __float_as_int(f), 0x114, 0xf, 0xf, false); // row_shr:4
  f += __int_as_float(t);
  t = __builtin_amdgcn_update_dpp(0, __float_as_int(f), 0x118, 0xf, 0xf, false); // row_shr:8
  f += __int_as_float(t);
  t = __builtin_amdgcn_update_dpp(0, __float_as_int(f), 0x142, 0xa, 0xf, false); // row_bcast:15
  f += __int_as_float(t);
  t = __builtin_amdgcn_update_dpp(0, __float_as_int(f), 0x143, 0xc, 0xf, false); // row_bcast:31
  f += __int_as_float(t);
  return f;
}

struct TR {
  float vp0, vm0, vp1, vm1;
  float ap0, am0, ap1, am1;
  float jp0, jm0, jp1, jm1;
  float pp0, pm0, pp1, pm1;
};

__device__ __forceinline__ void wpair(float tp, float tm, float& ws, float& wr) {
  float a = fmaxf(tp, 0.f), b = fmaxf(tm, 0.f);
  ws = b - a;
  wr = (tm - tp) - ws;
}

__device__ __forceinline__ void w_phase(const TR& t, int l, bool hi, float dth,
                                        float& os0, float& os1, float& or0, float& or1)
{
  float vs0, vr0, vs1, vr1, ys0, yr0, ys1, yr1;
  float zs0, zr0, zs1, zr1, ps0, pr0, ps1, pr1;
  wpair(t.vp0, t.vm0, vs0, vr0);
  wpair(t.ap0, t.am0, ys0, yr0);
  wpair(t.jp0, t.jm0, zs0, zr0);
  wpair(t.pp0, t.pm0, ps0, pr0);
  if (hi) { wpair(t.vp1, t.vm1, vs1, vr1); wpair(t.pp1, t.pm1, ps1, pr1); }
  else    { vs1 = vr1 = ps1 = pr1 = 0.f; }
  if (hi && l <= 34) { wpair(t.ap1, t.am1, ys1, yr1); } else { ys1 = yr1 = 0.f; }
  if (hi && l <= 33) { wpair(t.jp1, t.jm1, zs1, zr1); } else { zs1 = zr1 = 0.f; }

  const int lm1 = (l + 63) & 63, lm2 = (l + 62) & 63;
  float u1ys0 = __shfl(ys0, lm1), u1ys1 = __shfl(ys1, lm1);
  float u1zs0 = __shfl(zs0, lm1), u1zs1 = __shfl(zs1, lm1);
  float u2zs0 = __shfl(zs0, lm2), u2zs1 = __shfl(zs1, lm2);
  float u1yr0 = __shfl(yr0, lm1), u1yr1 = __shfl(yr1, lm1);
  float u1zr0 = __shfl(zr0, lm1), u1zr1 = __shfl(zr1, lm1);
  float u2zr0 = __shfl(zr0, lm2), u2zr1 = __shfl(zr1, lm2);

  float pa0s = ps0 + dth;
  float pa1s = hi ? ps1 + dth : 0.f;
  float pa0r = pr0;
  float pa1r = hi ? pr1 : 0.f;
  float s0s = iscan(pa0s);
  float s0r = iscan(pa0r);
  float tots = rdlane(s0s, 63), totr = rdlane(s0r, 63);
  float s1s = iscan(pa1s) + tots;
  float s1r = iscan(pa1r) + totr;
  float Ss = rdlane(s1s, 35), Sr = rdlane(s1r, 35);
  float rc0s = Ss - s0s + pa0s, rc1s = Ss - s1s + pa1s;
  float rc0r = Sr - s0r + pa0r, rc1r = Sr - s1r + pa1r;

  float ym1s0 = l ? u1ys0 : 0.f, zm1s0 = l ? u1zs0 : 0.f, zm2s0 = (l >= 2) ? u2zs0 : 0.f;
  float ym1r0 = l ? u1yr0 : 0.f, zm1r0 = l ? u1zr0 : 0.f, zm2r0 = (l >= 2) ? u2zr0 : 0.f;
  os0 = vs0 + 50.f * (ym1s0 - ys0) + 2500.f * (zm2s0 - 2.f * zm1s0 + zs0) + 0.02f * rc0s;
  or0 = vr0 + 50.f * (ym1r0 - yr0) + 2500.f * (zm2r0 - 2.f * zm1r0 + zr0) + 0.02f * rc0r;
  float ym1s1 = l ? u1ys1 : u1ys0, zm1s1 = l ? u1zs1 : u1zs0, zm2s1 = (l >= 2) ? u2zs1 : u2zs0;
  float ym1r1 = l ? u1yr1 : u1yr0, zm1r1 = l ? u1zr1 : u1zr0, zm2r1 = (l >= 2) ? u2zr1 : u2zr0;
  os1 = vs1 + 50.f * (ym1s1 - ys1) + 2500.f * (zm2s1 - 2.f * zm1s1 + zs1) + 0.02f * rc1s;
  or1 = vr1 + 50.f * (ym1r1 - yr1) + 2500.f * (zm2r1 - 2.f * zm1r1 + zr1) + 0.02f * rc1r;
}

__global__ __launch_bounds__(448, 4) void solver_kernel(const float* __restrict__ out2,
                                                        const float* __restrict__ input,
                                                        const float* __restrict__ theta,
                                                        const float* __restrict__ vstart,
                                                        const float* __restrict__ QtT,
                                                        float* __restrict__ out, int ldo)
{
  __shared__ __align__(16) float ru_t[112][12];
  __shared__ float pm[4][700];
  __shared__ float part[7][20][3];
  __shared__ float prfp[40];

  const int b = blockIdx.x, tid = threadIdx.x;
  const int d = tid >> 6, l = tid & 63;
  const bool hi = (l < 36);
  const int i2 = 64 + l;
  const float th = theta[b];
  const float dth = (d == 3) ? -2.f * th : 0.f;
  const float bp  = (d <= 3) ? (3.14f - th) : (3.14f + th);
  const float bm2 = (d <  3) ? (3.14f - th) : (3.14f + th);
  const float* orow = out2 + (size_t)b * ldo;
  const float* srow = orow + 700;

  float lam0 = orow[d * 100 + l];
  float xs0  = input[(size_t)b * NVARS + d * 100 + l];
  float lam1 = hi ? orow[d * 100 + i2] : 0.f;
  float xs1  = hi ? input[(size_t)b * NVARS + d * 100 + i2] : 0.f;

  TR t;
  {
    const int vb = d * 200, ab = 1400 + d * 198, jb = 2786 + d * 196, pb = 4158 + d * 200;
    t.vp0 = fmaxf(srow[vb + l], 0.f);        t.vm0 = fmaxf(srow[vb + 100 + l], 0.f);
    t.ap0 = fmaxf(srow[ab + l], 0.f);        t.am0 = fmaxf(srow[ab + 99 + l], 0.f);
    t.jp0 = fmaxf(srow[jb + l], 0.f);        t.jm0 = fmaxf(srow[jb + 98 + l], 0.f);
    t.pp0 = fmaxf(srow[pb + l], 0.f);        t.pm0 = fmaxf(srow[pb + 100 + l], 0.f);
    t.vp1 = hi        ? fmaxf(srow[vb + i2], 0.f)      : 0.f;
    t.vm1 = hi        ? fmaxf(srow[vb + 100 + i2], 0.f) : 0.f;
    t.ap1 = (l <= 34) ? fmaxf(srow[ab + i2], 0.f)      : 0.f;
    t.am1 = (l <= 34) ? fmaxf(srow[ab + 99 + i2], 0.f) : 0.f;
    t.jp1 = (l <= 33) ? fmaxf(srow[jb + i2], 0.f)      : 0.f;
    t.jm1 = (l <= 33) ? fmaxf(srow[jb + 98 + i2], 0.f) : 0.f;
    t.pp1 = hi        ? fmaxf(srow[pb + i2], 0.f)      : 0.f;
    t.pm1 = hi        ? fmaxf(srow[pb + 100 + i2], 0.f) : 0.f;
  }
  if (l == 0) ru_t[100][d] = vstart[b * 7 + d];
  for (int q = tid; q < 132; q += 448) ru_t[101 + q / 12][q % 12] = 0.f;

  {
    float os0, os1, or0, or1;
    w_phase(t, l, hi, dth, os0, os1, or0, or1);
    ru_t[l][d] = lam0 + xs0 + os0;
    if (hi) ru_t[i2][d] = lam1 + xs1 + os1;
  }

  for (int it = 0; it < MAXIT; ++it) {
    __syncthreads();
    {
      int kc = tid / 112, r = tid - kc * 112;
      if (r < 100) {
        const int k0 = kc * 28;
        float4 qv[7];
#pragma unroll
        for (int j = 0; j < 7; ++j)
          qv[j] = *reinterpret_cast<const float4*>(&QtT[r * 112 + k0 + j * 4]);
        float acc[7] = {0.f, 0.f, 0.f, 0.f, 0.f, 0.f, 0.f};
        const float* qs = reinterpret_cast<const float*>(qv);
#pragma unroll
        for (int jj = 0; jj < 28; ++jj) {
          float q = qs[jj];
          float4 ra = *reinterpret_cast<const float4*>(&ru_t[k0 + jj][0]);
          float4 rb = *reinterpret_cast<const float4*>(&ru_t[k0 + jj][4]);
          acc[0] += q * ra.x; acc[1] += q * ra.y; acc[2] += q * ra.z; acc[3] += q * ra.w;
          acc[4] += q * rb.x; acc[5] += q * rb.y; acc[6] += q * rb.z;
        }
#pragma unroll
        for (int dd = 0; dd < 7; ++dd) pm[kc][dd * 100 + r] = acc[dd];
      }
    }
    __syncthreads();

    float r2 = 0.f, ds2 = 0.f, dl2 = 0.f;
    {
      const int a0 = d * 100 + l;
      float x0 = pm[0][a0] + pm[1][a0] + pm[2][a0] + pm[3][a0];
      float x1 = 0.f;
      if (hi) {
        const int a1 = d * 100 + i2;
        x1 = pm[0][a1] + pm[1][a1] + pm[2][a1] + pm[3][a1];
      }
      const int lp1 = (l + 1) & 63, lp2 = (l + 2) & 63;
      float d1x0 = __shfl(x0, lp1), d1x1 = __shfl(x1, lp1);
      float d2x0 = __shfl(x0, lp2), d2x1 = __shfl(x1, lp2);
      float xp1_0 = (l == 63) ? d1x1 : d1x0;
      float xp2_0 = (l >= 62) ? d2x1 : d2x0;
      float xp1_1 = d1x1, xp2_1 = d2x1;
      float c0 = iscan(x0);
      float tt = rdlane(c0, 63);
      float c1 = iscan(hi ? x1 : 0.f) + tt;
#define NU(tp_, tm_, np_, nm_) { \
      float sop = fmaxf(tp_, 0.f), som = fmaxf(tm_, 0.f); \
      float snp = fmaxf(np_, 0.f), snm = fmaxf(nm_, 0.f); \
      float e1 = sop - snp, e2 = som - snm; ds2 += e1 * e1 + e2 * e2; \
      float q1 = snp - (np_), q2 = snm - (nm_); r2 += q1 * q1 + q2 * q2; \
      tp_ = np_; tm_ = nm_; }
      { float np = 1.f - x0, nm = 1.f + x0; NU(t.vp0, t.vm0, np, nm) }
      { float a = 50.f * (xp1_0 - x0); float np = 2.f - a, nm = 2.f + a; NU(t.ap0, t.am0, np, nm) }
      { float j = 2500.f * (xp2_0 - 2.f * xp1_0 + x0); float np = 5.f - j, nm = 5.f + j; NU(t.jp0, t.jm0, np, nm) }
      { float np = bp - 0.02f * c0, nm = bm2 + 0.02f * c0; NU(t.pp0, t.pm0, np, nm) }
      if (hi) {
        { float np = 1.f - x1, nm = 1.f + x1; NU(t.vp1, t.vm1, np, nm) }
        { float np = bp - 0.02f * c1, nm = bm2 + 0.02f * c1; NU(t.pp1, t.pm1, np, nm) }
      }
      if (l <= 34) { float a = 50.f * (xp1_1 - x1); float np = 2.f - a, nm = 2.f + a; NU(t.ap1, t.am1, np, nm) }
      if (l <= 33) { float j = 2500.f * (xp2_1 - 2.f * xp1_1 + x1); float np = 5.f - j, nm = 5.f + j; NU(t.jp1, t.jm1, np, nm) }
#undef NU
    }

    {
      float os0, os1, or0, or1;
      w_phase(t, l, hi, dth, os0, os1, or0, or1);
      lam0 -= or0; dl2 += or0 * or0;
      ru_t[l][d] = lam0 + xs0 + os0;
      if (hi) {
        lam1 -= or1; dl2 += or1 * or1;
        ru_t[i2][d] = lam1 + xs1 + os1;
      }
    }

    r2 = iscan(r2); ds2 = iscan(ds2); dl2 = iscan(dl2);
    if (l == 63) { part[d][it][0] = r2; part[d][it][1] = ds2; part[d][it][2] = dl2; }
  }

  __syncthreads();
  {
    const int a0 = d * 100 + l;
    float x0 = pm[0][a0] + pm[1][a0] + pm[2][a0] + pm[3][a0];
    float* xout = out + (size_t)b * NVARS + d * 100;
    xout[l] = x0;
    if (hi) {
      const int a1 = d * 100 + i2;
      xout[i2] = pm[0][a1] + pm[1][a1] + pm[2][a1] + pm[3][a1];
    }
  }
  if (tid < 20) {
    int it = tid;
    float R2 = 0.f, DS2 = 0.f, DL2 = 0.f;
    for (int dd = 0; dd < 7; ++dd) {
      R2 += part[dd][it][0]; DS2 += part[dd][it][1]; DL2 += part[dd][it][2];
    }
    float pr = sqrtf(R2), fp = sqrtf(DL2) + sqrtf(DS2);
    out[718848 + it * 1024 + b] = pr;
    out[739328 + it * 1024 + b] = fp;
    prfp[it] = pr; prfp[20 + it] = fp;
  }
  __syncthreads();
  if (tid == 0) {
    float ap = 0.f, af = 0.f;
    for (int it = 0; it < 20; ++it) { ap += prfp[it]; af += prfp[20 + it]; }
    out[716800 + b] = af / 20.f;
    out[717824 + b] = ap / 20.f;
  }
}

// =====================================================================
extern "C" void kernel_launch(void* const* d_in, const int* in_sizes, int n_in,
                              void* d_out, int out_size, void* d_ws, size_t ws_size,
                              hipStream_t stream) {
  (void)in_sizes; (void)n_in; (void)out_size;
  const float* input  = (const float*)d_in[0];
  const float* theta  = (const float*)d_in[1];
  const float* vstart = (const float*)d_in[2];
  const float* W1     = (const float*)d_in[3];
  const float* b1     = (const float*)d_in[4];
  const float* W2     = (const float*)d_in[5];
  const float* b2     = (const float*)d_in[6];
  float* out = (float*)d_out;

  float* wsf  = (float*)d_ws;
  double* cid = (double*)d_ws;         // 10000 f64 = 20000 slots
  float* QtT  = wsf + 20000;           // 100*112
  float* med  = wsf + 31200;
  float* rinv = wsf + 31900;

  hipLaunchKernelGGL(qinv_kernel, dim3(1), dim3(128), 0, stream, cid, QtT);
  hipLaunchKernelGGL(quantile_kernel, dim3(700), dim3(256), 0, stream, input, med, rinv);

  const size_t HHI = 32600, HLO = 556888, W2TH = 1081176, W2TL = 4292440,
               OUT2 = 7503704, NEED = 13926232;
  const size_t ANH = OUT2, ANL = OUT2 + 360448, W1TH = OUT2 + 720896, W1TL = OUT2 + 1081344;

  if (ws_size >= NEED * 4ull) {
    ushort* an_h  = (ushort*)(wsf + ANH);
    ushort* an_l  = (ushort*)(wsf + ANL);
    ushort* w1t_h = (ushort*)(wsf + W1TH);
    ushort* w1t_l = (ushort*)(wsf + W1TL);
    ushort* h_h   = (ushort*)(wsf + HHI);
    ushort* h_l   = (ushort*)(wsf + HLO);
    ushort* w2t_h = (ushort*)(wsf + W2TH);
    ushort* w2t_l = (ushort*)(wsf + W2TL);
    float*  out2  = wsf + OUT2;

    hipLaunchKernelGGL(normalize_split, dim3((1024 * 704 + 255) / 256), dim3(256), 0, stream,
                       input, med, rinv, an_h, an_l);
    hipLaunchKernelGGL(tsplit, dim3(22, 32), dim3(32, 8), 0, stream,
                       W1, 700, 1024, 1024, 0, w1t_h, w1t_l, 704);
    hipLaunchKernelGGL(tsplit, dim3(32, 196), dim3(32, 8), 0, stream,
                       W2, 1024, 6958, 6958, 700, w2t_h, w2t_l, 1024);
    // gemm1: nbx=16 (N=1024/64), nby=16 (M=1024/64); 256 blocks, chunk=32
    hipLaunchKernelGGL((gemm_mfma<64, 64, 1>), dim3(256), dim3(256), 0, stream,
                       an_h, an_l, w1t_h, w1t_l, b1, 1024,
                       (float*)nullptr, h_h, h_l, 704, 1024, 16, 32);
    // gemm2: nbx=49 (N=6272/128), nby=16 (M=1024/64); 784 blocks, chunk=98
    hipLaunchKernelGGL((gemm_mfma<64, 128, 0>), dim3(784), dim3(256), 0, stream,
                       h_h, h_l, w2t_h, w2t_l, b2 + 700, 6258,
                       out2, (ushort*)nullptr, (ushort*)nullptr, 1024, 6272, 16, 98);
    hipLaunchKernelGGL(solver_kernel, dim3(1024), dim3(448), 0, stream,
                       out2, input, theta, vstart, QtT, out, 6272);
  } else {
    float* An   = wsf + 32600;
    float* h    = wsf + 749400;
    float* out2 = wsf + 1797976;
    if (ws_size < (size_t)(1797976 + 6408192) * 4) return;
    hipLaunchKernelGGL(normalize_kernel, dim3(2800), dim3(256), 0, stream, input, med, rinv, An);
    hipLaunchKernelGGL((gemm_kernel<true>), dim3(16, 16), dim3(256), 0, stream,
                       An, NVARS, W1, 1024, b1, h, 1024, 1024, NVARS);
    hipLaunchKernelGGL((gemm_kernel<false>), dim3(98, 16), dim3(256), 0, stream,
                       h, 1024, W2 + 700, 6958, b2 + 700, out2, 6258, 6258, 1024);
    hipLaunchKernelGGL(solver_kernel, dim3(1024), dim3(448), 0, stream,
                       out2, input, theta, vstart, QtT, out, 6258);
  }
}

// Round 9
// 565.846 us; speedup vs baseline: 1.2231x; 1.0018x over previous
//
#include <hip/hip_runtime.h>

// ---------------- problem constants ----------------
#define NVARS 700
#define MC    5558
#define MAXIT 20

typedef __attribute__((ext_vector_type(8))) short bf16x8;
typedef __attribute__((ext_vector_type(4))) float f32x4;

__device__ __forceinline__ ushort f2bf(float x) {
  unsigned u = __float_as_uint(x);
  return (ushort)((u + 0x7FFFu + ((u >> 16) & 1u)) >> 16);
}

// =====================================================================
// qinv v2 (unchanged from R7)
// =====================================================================
__device__ __forceinline__ double Wfun(int a, int b) {
  if (a < 0 || a > 99 || b < 0 || b > 99) return 0.0;
  int d = a - b; if (d < 0) d = -d;
  int l = a < b ? a : b;
  const double iT2 = 2500.0;
  const double iT4 = 6250000.0;
  double w = 0.0;
  if (d == 0) {
    w = 3.0;
    w += 2.0 * iT2 * (double)((a <= 98 ? 1 : 0) + (a >= 1 ? 1 : 0));
    double dd = (double)(((a - 2) >= 0 && (a - 2) <= 97) ? 1 : 0)
              + 4.0 * (double)(((a - 1) >= 0 && (a - 1) <= 97) ? 1 : 0)
              + (double)((a <= 97) ? 1 : 0);
    w += 2.0 * iT4 * dd;
  } else if (d == 1) {
    w = -2.0 * iT2;
    double dd = -2.0 * (double)(((l - 1) >= 0 && (l - 1) <= 97) ? 1 : 0)
                - 2.0 * (double)((l <= 97) ? 1 : 0);
    w += 2.0 * iT4 * dd;
  } else if (d == 2) {
    w = 2.0 * iT4 * (double)((l <= 97) ? 1 : 0);
  }
  return w;
}

__global__ __launch_bounds__(128) void qinv_kernel(double* __restrict__ cid,
                                                   float* __restrict__ QtT)
{
  __shared__ double Bb[100][4];
  __shared__ double Gb[100][4];
  __shared__ double invd[100];
  __shared__ double zl[100][52];
  int tid = threadIdx.x;
  for (int q = tid; q < 400; q += 128) {
    int i = q >> 2, k = q & 3;
    int j = i - k;
    double v = 0.0;
    if (j >= 0) {
      v = Wfun(i, j) - Wfun(i + 1, j) - Wfun(i, j + 1) + Wfun(i + 1, j + 1);
      if (k == 0) v += 2.0 * 0.02 * 0.02;
    }
    Bb[i][k] = v;
  }
  __syncthreads();
  if (tid == 0) {
    for (int i = 0; i < 100; ++i) {
      for (int k = 3; k >= 1; --k) {
        int j = i - k;
        if (j < 0) { Gb[i][k] = 0.0; continue; }
        double s = Bb[i][k];
        for (int m = k + 1; m <= 3; ++m)
          if (m <= i) s -= Gb[i][m] * Gb[j][m - k];
        Gb[i][k] = s * invd[j];
      }
      double s = Bb[i][0];
      for (int m = 1; m <= 3; ++m)
        if (m <= i) s -= Gb[i][m] * Gb[i][m];
      double g = sqrt(s);
      Gb[i][0] = g;
      invd[i] = 1.0 / g;
    }
  }
  __syncthreads();
  for (int bb = 0; bb < 2; ++bb) {
    if (tid < 50) {
      int c = bb * 50 + tid;
      double z0 = 0, z1 = 0, z2 = 0;
      for (int i = 0; i < 100; ++i) {
        double v = (i == c ? 1.0 : 0.0) - (i == (c - 1) ? 1.0 : 0.0);
        double s = v - Gb[i][1] * z0 - Gb[i][2] * z1 - Gb[i][3] * z2;
        double z = s * invd[i];
        zl[i][tid] = z;
        z2 = z1; z1 = z0; z0 = z;
      }
      double y0 = 0, y1 = 0, y2 = 0;
      for (int i = 99; i >= 0; --i) {
        double s = zl[i][tid];
        if (i + 1 <= 99) s -= Gb[i + 1][1] * y0;
        if (i + 2 <= 99) s -= Gb[i + 2][2] * y1;
        if (i + 3 <= 99) s -= Gb[i + 3][3] * y2;
        double y = s * invd[i];
        zl[i][tid] = y;
        y2 = y1; y1 = y0; y0 = y;
      }
      double ym = 0.0;
      for (int i = 0; i < 100; ++i) {
        double y = zl[i][tid];
        cid[i * 100 + c] = y - ym;
        ym = y;
      }
    }
    __syncthreads();
  }
  double invs = 1.0 / cid[0];
  for (int q = tid; q < 100 * 112; q += 128) {
    int i = q / 112, k = q - i * 112;
    double val = 0.0;
    if (k < 100)       val = cid[i * 100 + k] - cid[i * 100] * cid[k] * invs;
    else if (k == 100) val = cid[i * 100] * invs;
    QtT[q] = (float)val;
  }
}

// =====================================================================
// quantiles (unchanged)
// =====================================================================
__global__ __launch_bounds__(256) void quantile_kernel(const float* __restrict__ in,
                                                       float* __restrict__ med,
                                                       float* __restrict__ rinv)
{
  __shared__ float v[1024];
  int c = blockIdx.x, tid = threadIdx.x;
  for (int i = tid; i < 1024; i += 256) v[i] = in[i * NVARS + c];
  __syncthreads();
  for (int k = 2; k <= 1024; k <<= 1) {
    for (int j = k >> 1; j > 0; j >>= 1) {
      for (int i = tid; i < 1024; i += 256) {
        int ixj = i ^ j;
        if (ixj > i) {
          float a = v[i], b2 = v[ixj];
          bool up = ((i & k) == 0);
          if ((a > b2) == up) { v[i] = b2; v[ixj] = a; }
        }
      }
      __syncthreads();
    }
  }
  if (tid == 0) {
    float m  = v[511];
    float q1 = v[255] + 0.75f * (v[256] - v[255]);
    float q3 = v[767] + 0.25f * (v[768] - v[767]);
    float iq = q3 - q1;
    if (iq == 0.f) iq = 1.f;
    med[c] = m;
    rinv[c] = 1.f / iq;
  }
}

// ---- normalize + split to bf16 hi/lo, padded K=704 ----
__global__ __launch_bounds__(256) void normalize_split(const float* __restrict__ in,
                                                       const float* __restrict__ med,
                                                       const float* __restrict__ rinv,
                                                       ushort* __restrict__ Ah,
                                                       ushort* __restrict__ Al)
{
  int idx = blockIdx.x * 256 + threadIdx.x;
  if (idx >= 1024 * 704) return;
  int r = idx / 704, c = idx - r * 704;
  float v = 0.f;
  if (c < 700) v = (in[r * NVARS + c] - med[c]) * rinv[c];
  ushort h = f2bf(v);
  float fh = __uint_as_float(((unsigned)h) << 16);
  Ah[idx] = h;
  Al[idx] = f2bf(v - fh);
}

// ---- transpose + split: dst[n][k] = src[k][col0+n], zero padded ----
__global__ __launch_bounds__(256) void tsplit(const float* __restrict__ src,
                                              int srows, int scols, int sld, int col0,
                                              ushort* __restrict__ dh,
                                              ushort* __restrict__ dl, int dld)
{
  __shared__ float tile[32][33];
  int k0 = blockIdx.x * 32, n0 = blockIdx.y * 32;
  int tx = threadIdx.x, ty = threadIdx.y;   // (32, 8)
  for (int i = ty; i < 32; i += 8) {
    int k = k0 + i, c = col0 + n0 + tx;
    tile[i][tx] = (k < srows && c < scols) ? src[(size_t)k * sld + c] : 0.f;
  }
  __syncthreads();
  for (int i = ty; i < 32; i += 8) {
    int n = n0 + i, k = k0 + tx;
    float v = tile[tx][i];
    ushort h = f2bf(v);
    float fh = __uint_as_float(((unsigned)h) << 16);
    dh[(size_t)n * dld + k] = h;
    dl[(size_t)n * dld + k] = f2bf(v - fh);
  }
}

// =====================================================================
// MFMA GEMM, bf16 hi/lo split, XCD swizzle, LDS-staged coalesced epilogue.
// Epilogue: stage 32-row x BN f32 slice in LDS (aliased over K-loop bufs),
// then full-line cooperative writes (float4 / uint4) - kills the R8
// partial-line write amplification (WRITE 245MB vs 25.7MB ideal).
// =====================================================================
template <int BM, int BN, int MODE>
__global__ __launch_bounds__(256) void gemm_mfma(
    const ushort* __restrict__ Agh, const ushort* __restrict__ Agl,
    const ushort* __restrict__ Bgh, const ushort* __restrict__ Bgl,
    const float* __restrict__ bias, int bias_n,
    float* __restrict__ Cf, ushort* __restrict__ Chi, ushort* __restrict__ Clo,
    int Kp, int ldc, int nby, int chunk)
{
  constexpr int ACH = BM * 4 / 256;
  constexpr int BCH = BN * 4 / 256;
  constexpr int MF = BM / 32;
  constexpr int NF = BN / 32;
  constexpr int KL_BYTES = (BM * 40 + BN * 40) * 2 * 2;    // hi+lo, A+B
  constexpr int CST_BYTES = 32 * (BN + 4) * 4;
  constexpr int SMEM = KL_BYTES > CST_BYTES ? KL_BYTES : CST_BYTES;
  __shared__ __align__(16) char smem[SMEM];
  ushort* Ash = (ushort*)smem;
  ushort* Asl = Ash + BM * 40;
  ushort* Bsh = Asl + BM * 40;
  ushort* Bsl = Bsh + BN * 40;
  float (*cst)[BN + 4] = (float (*)[BN + 4])smem;

  const int t = threadIdx.x;
  const int wg = blockIdx.x;
  const int gid = (wg & 7) * chunk + (wg >> 3);
  const int bxi = gid / nby, byi = gid - bxi * nby;
  const size_t bm = (size_t)byi * BM;
  const size_t bn = (size_t)bxi * BN;

  size_t aoff[ACH]; int awo[ACH];
#pragma unroll
  for (int s = 0; s < ACH; ++s) {
    int slot = t * ACH + s, row = slot >> 2, ch = slot & 3;
    aoff[s] = (bm + row) * (size_t)Kp + ch * 8;
    awo[s] = row * 40 + ch * 8;
  }
  size_t boff[BCH]; int bwo[BCH];
#pragma unroll
  for (int s = 0; s < BCH; ++s) {
    int slot = t * BCH + s, row = slot >> 2, ch = slot & 3;
    boff[s] = (bn + row) * (size_t)Kp + ch * 8;
    bwo[s] = row * 40 + ch * 8;
  }

  const int w = t >> 6, lane = t & 63;
  const int wr = w >> 1, wc = w & 1;
  const int fr = lane & 15, fg = lane >> 4;

  f32x4 acc[MF][NF];
#pragma unroll
  for (int a = 0; a < MF; ++a)
#pragma unroll
    for (int b = 0; b < NF; ++b) acc[a][b] = (f32x4){0.f, 0.f, 0.f, 0.f};

  const int nk = Kp >> 5;
  uint4 rAh[ACH], rAl[ACH], rBh[BCH], rBl[BCH];
#pragma unroll
  for (int s = 0; s < ACH; ++s) { rAh[s] = *(const uint4*)(Agh + aoff[s]); rAl[s] = *(const uint4*)(Agl + aoff[s]); }
#pragma unroll
  for (int s = 0; s < BCH; ++s) { rBh[s] = *(const uint4*)(Bgh + boff[s]); rBl[s] = *(const uint4*)(Bgl + boff[s]); }

  for (int kt = 0;; ++kt) {
    __syncthreads();
#pragma unroll
    for (int s = 0; s < ACH; ++s) { *(uint4*)&Ash[awo[s]] = rAh[s]; *(uint4*)&Asl[awo[s]] = rAl[s]; }
#pragma unroll
    for (int s = 0; s < BCH; ++s) { *(uint4*)&Bsh[bwo[s]] = rBh[s]; *(uint4*)&Bsl[bwo[s]] = rBl[s]; }
    __syncthreads();
    if (kt + 1 < nk) {
      int ko = (kt + 1) * 32;
#pragma unroll
      for (int s = 0; s < ACH; ++s) { rAh[s] = *(const uint4*)(Agh + aoff[s] + ko); rAl[s] = *(const uint4*)(Agl + aoff[s] + ko); }
#pragma unroll
      for (int s = 0; s < BCH; ++s) { rBh[s] = *(const uint4*)(Bgh + boff[s] + ko); rBl[s] = *(const uint4*)(Bgl + boff[s] + ko); }
    }
    bf16x8 fah[MF], fal[MF], fbh[NF], fbl[NF];
#pragma unroll
    for (int mf = 0; mf < MF; ++mf) {
      int off = (wr * (BM / 2) + mf * 16 + fr) * 40 + fg * 8;
      fah[mf] = *(const bf16x8*)&Ash[off];
      fal[mf] = *(const bf16x8*)&Asl[off];
    }
#pragma unroll
    for (int nf = 0; nf < NF; ++nf) {
      int off = (wc * (BN / 2) + nf * 16 + fr) * 40 + fg * 8;
      fbh[nf] = *(const bf16x8*)&Bsh[off];
      fbl[nf] = *(const bf16x8*)&Bsl[off];
    }
#pragma unroll
    for (int mf = 0; mf < MF; ++mf)
#pragma unroll
      for (int nf = 0; nf < NF; ++nf) {
        acc[mf][nf] = __builtin_amdgcn_mfma_f32_16x16x32_bf16(fah[mf], fbh[nf], acc[mf][nf], 0, 0, 0);
        acc[mf][nf] = __builtin_amdgcn_mfma_f32_16x16x32_bf16(fah[mf], fbl[nf], acc[mf][nf], 0, 0, 0);
        acc[mf][nf] = __builtin_amdgcn_mfma_f32_16x16x32_bf16(fal[mf], fbh[nf], acc[mf][nf], 0, 0, 0);
      }
    if (kt + 1 >= nk) break;
  }

  // ---- epilogue: LDS-staged, full-line coalesced global writes ----
#pragma unroll
  for (int mf = 0; mf < MF; ++mf) {
    __syncthreads();   // K-loop frag reads (or previous slice reads) complete
#pragma unroll
    for (int nf = 0; nf < NF; ++nf) {
      int lc = wc * (BN / 2) + nf * 16 + fr;
      int gcol = (int)bn + lc;
      float bv = (MODE == 0) ? ((gcol < bias_n) ? bias[gcol] : 0.f) : bias[gcol];
#pragma unroll
      for (int j = 0; j < 4; ++j)
        cst[wr * 16 + fg * 4 + j][lc] = acc[mf][nf][j] + bv;
    }
    __syncthreads();   // slice staged
    if (MODE == 0) {
      constexpr int TPR = BN / 4;        // threads per row (float4)
      constexpr int RPP = 256 / TPR;     // rows per pass
#pragma unroll
      for (int p = 0; p < 32 / RPP; ++p) {
        int lr = p * RPP + t / TPR;
        int c0 = (t % TPR) * 4;
        int grow = (int)bm + (lr >> 4) * (BM / 2) + mf * 16 + (lr & 15);
        float4 v = *(const float4*)&cst[lr][c0];
        *(float4*)&Cf[(size_t)grow * ldc + bn + c0] = v;
      }
    } else {
      int lr = t >> 3;                   // 32 rows x 8 threads/row (BN=64)
      int c0 = (t & 7) * 8;
      int grow = (int)bm + (lr >> 4) * (BM / 2) + mf * 16 + (lr & 15);
      ushort hi8[8], lo8[8];
#pragma unroll
      for (int q = 0; q < 8; ++q) {
        float r = fmaxf(cst[lr][c0 + q], 0.f);
        ushort hh = f2bf(r);
        float fh = __uint_as_float(((unsigned)hh) << 16);
        hi8[q] = hh; lo8[q] = f2bf(r - fh);
      }
      *(uint4*)&Chi[(size_t)grow * ldc + bn + c0] = *(const uint4*)hi8;
      *(uint4*)&Clo[(size_t)grow * ldc + bn + c0] = *(const uint4*)lo8;
    }
  }
}

// =====================================================================
// fallback path: f32 normalize + SIMT GEMM (unchanged)
// =====================================================================
__global__ __launch_bounds__(256) void normalize_kernel(const float* __restrict__ in,
                                                        const float* __restrict__ med,
                                                        const float* __restrict__ rinv,
                                                        float* __restrict__ An)
{
  int idx = blockIdx.x * 256 + threadIdx.x;
  if (idx < 1024 * NVARS) {
    int c = idx % NVARS;
    An[idx] = (in[idx] - med[c]) * rinv[c];
  }
}

template <bool RELU>
__global__ __launch_bounds__(256) void gemm_kernel(const float* __restrict__ A, int lda,
                                                   const float* __restrict__ B, int ldb,
                                                   const float* __restrict__ bias,
                                                   float* __restrict__ C, int ldc,
                                                   int N, int K)
{
  __shared__ __align__(16) float As[16][68];
  __shared__ __align__(16) float Bs[16][64];
  int tid = threadIdx.x;
  int bm = blockIdx.y * 64, bn = blockIdx.x * 64;
  int tx = tid & 15, ty = tid >> 4;
  float acc[4][4] = {};
  for (int k0 = 0; k0 < K; k0 += 16) {
    {
      int q = tid * 4;
      int m = q >> 4, kk = q & 15;
      const float* ap = A + (size_t)(bm + m) * lda + k0;
#pragma unroll
      for (int s2 = 0; s2 < 4; ++s2) {
        int kc = kk + s2;
        As[kc][m] = (k0 + kc < K) ? ap[kc] : 0.f;
      }
    }
#pragma unroll
    for (int s2 = 0; s2 < 4; ++s2) {
      int q = tid + s2 * 256;
      int kk = q >> 6, n = q & 63;
      float val = 0.f;
      if (k0 + kk < K && bn + n < N) val = B[(size_t)(k0 + kk) * ldb + bn + n];
      Bs[kk][n] = val;
    }
    __syncthreads();
#pragma unroll
    for (int kk = 0; kk < 16; ++kk) {
      float4 av = *reinterpret_cast<const float4*>(&As[kk][ty * 4]);
      float4 bv = *reinterpret_cast<const float4*>(&Bs[kk][tx * 4]);
      acc[0][0] += av.x * bv.x; acc[0][1] += av.x * bv.y; acc[0][2] += av.x * bv.z; acc[0][3] += av.x * bv.w;
      acc[1][0] += av.y * bv.x; acc[1][1] += av.y * bv.y; acc[1][2] += av.y * bv.z; acc[1][3] += av.y * bv.w;
      acc[2][0] += av.z * bv.x; acc[2][1] += av.z * bv.y; acc[2][2] += av.z * bv.z; acc[2][3] += av.z * bv.w;
      acc[3][0] += av.w * bv.x; acc[3][1] += av.w * bv.y; acc[3][2] += av.w * bv.z; acc[3][3] += av.w * bv.w;
    }
    __syncthreads();
  }
#pragma unroll
  for (int i = 0; i < 4; ++i) {
    int m = bm + ty * 4 + i;
#pragma unroll
    for (int j = 0; j < 4; ++j) {
      int n = bn + tx * 4 + j;
      if (n < N) {
        float r = acc[i][j] + bias[n];
        if (RELU) r = fmaxf(r, 0.f);
        C[(size_t)m * ldc + n] = r;
      }
    }
  }
}

// =====================================================================
// solver v5 (unchanged from R7)
// =====================================================================
__device__ __forceinline__ float rdlane(float v, int lane) {
  return __int_as_float(__builtin_amdgcn_readlane(__float_as_int(v), lane));
}

__device__ __forceinline__ float iscan(float v) {
  float f = v;
  int t;
  t = __builtin_amdgcn_update_dpp(0, __float_as_int(f), 0x111, 0xf, 0xf, false); // row_shr:1
  f += __int_as_float(t);
  t = __builtin_amdgcn_update_dpp(0, __float_as_int(f), 0x112, 0xf, 0xf, false); // row_shr:2
  f += __int_as_float(t);
  t = __builtin_amdgcn_update_dpp(0, __float_as_int(f), 0x114, 0xf, 0xf, false); // row_shr:4
  f += __int_as_float(t);
  t = __builtin_amdgcn_update_dpp(0, __float_as_int(f), 0x118, 0xf, 0xf, false); // row_shr:8
  f += __int_as_float(t);
  t = __builtin_amdgcn_update_dpp(0, __float_as_int(f), 0x142, 0xa, 0xf, false); // row_bcast:15
  f += __int_as_float(t);
  t = __builtin_amdgcn_update_dpp(0, __float_as_int(f), 0x143, 0xc, 0xf, false); // row_bcast:31
  f += __int_as_float(t);
  return f;
}

struct TR {
  float vp0, vm0, vp1, vm1;
  float ap0, am0, ap1, am1;
  float jp0, jm0, jp1, jm1;
  float pp0, pm0, pp1, pm1;
};

__device__ __forceinline__ void wpair(float tp, float tm, float& ws, float& wr) {
  float a = fmaxf(tp, 0.f), b = fmaxf(tm, 0.f);
  ws = b - a;
  wr = (tm - tp) - ws;
}

__device__ __forceinline__ void w_phase(const TR& t, int l, bool hi, float dth,
                                        float& os0, float& os1, float& or0, float& or1)
{
  float vs0, vr0, vs1, vr1, ys0, yr0, ys1, yr1;
  float zs0, zr0, zs1, zr1, ps0, pr0, ps1, pr1;
  wpair(t.vp0, t.vm0, vs0, vr0);
  wpair(t.ap0, t.am0, ys0, yr0);
  wpair(t.jp0, t.jm0, zs0, zr0);
  wpair(t.pp0, t.pm0, ps0, pr0);
  if (hi) { wpair(t.vp1, t.vm1, vs1, vr1); wpair(t.pp1, t.pm1, ps1, pr1); }
  else    { vs1 = vr1 = ps1 = pr1 = 0.f; }
  if (hi && l <= 34) { wpair(t.ap1, t.am1, ys1, yr1); } else { ys1 = yr1 = 0.f; }
  if (hi && l <= 33) { wpair(t.jp1, t.jm1, zs1, zr1); } else { zs1 = zr1 = 0.f; }

  const int lm1 = (l + 63) & 63, lm2 = (l + 62) & 63;
  float u1ys0 = __shfl(ys0, lm1), u1ys1 = __shfl(ys1, lm1);
  float u1zs0 = __shfl(zs0, lm1), u1zs1 = __shfl(zs1, lm1);
  float u2zs0 = __shfl(zs0, lm2), u2zs1 = __shfl(zs1, lm2);
  float u1yr0 = __shfl(yr0, lm1), u1yr1 = __shfl(yr1, lm1);
  float u1zr0 = __shfl(zr0, lm1), u1zr1 = __shfl(zr1, lm1);
  float u2zr0 = __shfl(zr0, lm2), u2zr1 = __shfl(zr1, lm2);

  float pa0s = ps0 + dth;
  float pa1s = hi ? ps1 + dth : 0.f;
  float pa0r = pr0;
  float pa1r = hi ? pr1 : 0.f;
  float s0s = iscan(pa0s);
  float s0r = iscan(pa0r);
  float tots = rdlane(s0s, 63), totr = rdlane(s0r, 63);
  float s1s = iscan(pa1s) + tots;
  float s1r = iscan(pa1r) + totr;
  float Ss = rdlane(s1s, 35), Sr = rdlane(s1r, 35);
  float rc0s = Ss - s0s + pa0s, rc1s = Ss - s1s + pa1s;
  float rc0r = Sr - s0r + pa0r, rc1r = Sr - s1r + pa1r;

  float ym1s0 = l ? u1ys0 : 0.f, zm1s0 = l ? u1zs0 : 0.f, zm2s0 = (l >= 2) ? u2zs0 : 0.f;
  float ym1r0 = l ? u1yr0 : 0.f, zm1r0 = l ? u1zr0 : 0.f, zm2r0 = (l >= 2) ? u2zr0 : 0.f;
  os0 = vs0 + 50.f * (ym1s0 - ys0) + 2500.f * (zm2s0 - 2.f * zm1s0 + zs0) + 0.02f * rc0s;
  or0 = vr0 + 50.f * (ym1r0 - yr0) + 2500.f * (zm2r0 - 2.f * zm1r0 + zr0) + 0.02f * rc0r;
  float ym1s1 = l ? u1ys1 : u1ys0, zm1s1 = l ? u1zs1 : u1zs0, zm2s1 = (l >= 2) ? u2zs1 : u2zs0;
  float ym1r1 = l ? u1yr1 : u1yr0, zm1r1 = l ? u1zr1 : u1zr0, zm2r1 = (l >= 2) ? u2zr1 : u2zr0;
  os1 = vs1 + 50.f * (ym1s1 - ys1) + 2500.f * (zm2s1 - 2.f * zm1s1 + zs1) + 0.02f * rc1s;
  or1 = vr1 + 50.f * (ym1r1 - yr1) + 2500.f * (zm2r1 - 2.f * zm1r1 + zr1) + 0.02f * rc1r;
}

__global__ __launch_bounds__(448, 4) void solver_kernel(const float* __restrict__ out2,
                                                        const float* __restrict__ input,
                                                        const float* __restrict__ theta,
                                                        const float* __restrict__ vstart,
                                                        const float* __restrict__ QtT,
                                                        float* __restrict__ out, int ldo)
{
  __shared__ __align__(16) float ru_t[112][12];
  __shared__ float pm[4][700];
  __shared__ float part[7][20][3];
  __shared__ float prfp[40];

  const int b = blockIdx.x, tid = threadIdx.x;
  const int d = tid >> 6, l = tid & 63;
  const bool hi = (l < 36);
  const int i2 = 64 + l;
  const float th = theta[b];
  const float dth = (d == 3) ? -2.f * th : 0.f;
  const float bp  = (d <= 3) ? (3.14f - th) : (3.14f + th);
  const float bm2 = (d <  3) ? (3.14f - th) : (3.14f + th);
  const float* orow = out2 + (size_t)b * ldo;
  const float* srow = orow + 700;

  float lam0 = orow[d * 100 + l];
  float xs0  = input[(size_t)b * NVARS + d * 100 + l];
  float lam1 = hi ? orow[d * 100 + i2] : 0.f;
  float xs1  = hi ? input[(size_t)b * NVARS + d * 100 + i2] : 0.f;

  TR t;
  {
    const int vb = d * 200, ab = 1400 + d * 198, jb = 2786 + d * 196, pb = 4158 + d * 200;
    t.vp0 = fmaxf(srow[vb + l], 0.f);        t.vm0 = fmaxf(srow[vb + 100 + l], 0.f);
    t.ap0 = fmaxf(srow[ab + l], 0.f);        t.am0 = fmaxf(srow[ab + 99 + l], 0.f);
    t.jp0 = fmaxf(srow[jb + l], 0.f);        t.jm0 = fmaxf(srow[jb + 98 + l], 0.f);
    t.pp0 = fmaxf(srow[pb + l], 0.f);        t.pm0 = fmaxf(srow[pb + 100 + l], 0.f);
    t.vp1 = hi        ? fmaxf(srow[vb + i2], 0.f)      : 0.f;
    t.vm1 = hi        ? fmaxf(srow[vb + 100 + i2], 0.f) : 0.f;
    t.ap1 = (l <= 34) ? fmaxf(srow[ab + i2], 0.f)      : 0.f;
    t.am1 = (l <= 34) ? fmaxf(srow[ab + 99 + i2], 0.f) : 0.f;
    t.jp1 = (l <= 33) ? fmaxf(srow[jb + i2], 0.f)      : 0.f;
    t.jm1 = (l <= 33) ? fmaxf(srow[jb + 98 + i2], 0.f) : 0.f;
    t.pp1 = hi        ? fmaxf(srow[pb + i2], 0.f)      : 0.f;
    t.pm1 = hi        ? fmaxf(srow[pb + 100 + i2], 0.f) : 0.f;
  }
  if (l == 0) ru_t[100][d] = vstart[b * 7 + d];
  for (int q = tid; q < 132; q += 448) ru_t[101 + q / 12][q % 12] = 0.f;

  {
    float os0, os1, or0, or1;
    w_phase(t, l, hi, dth, os0, os1, or0, or1);
    ru_t[l][d] = lam0 + xs0 + os0;
    if (hi) ru_t[i2][d] = lam1 + xs1 + os1;
  }

  for (int it = 0; it < MAXIT; ++it) {
    __syncthreads();
    {
      int kc = tid / 112, r = tid - kc * 112;
      if (r < 100) {
        const int k0 = kc * 28;
        float4 qv[7];
#pragma unroll
        for (int j = 0; j < 7; ++j)
          qv[j] = *reinterpret_cast<const float4*>(&QtT[r * 112 + k0 + j * 4]);
        float acc[7] = {0.f, 0.f, 0.f, 0.f, 0.f, 0.f, 0.f};
        const float* qs = reinterpret_cast<const float*>(qv);
#pragma unroll
        for (int jj = 0; jj < 28; ++jj) {
          float q = qs[jj];
          float4 ra = *reinterpret_cast<const float4*>(&ru_t[k0 + jj][0]);
          float4 rb = *reinterpret_cast<const float4*>(&ru_t[k0 + jj][4]);
          acc[0] += q * ra.x; acc[1] += q * ra.y; acc[2] += q * ra.z; acc[3] += q * ra.w;
          acc[4] += q * rb.x; acc[5] += q * rb.y; acc[6] += q * rb.z;
        }
#pragma unroll
        for (int dd = 0; dd < 7; ++dd) pm[kc][dd * 100 + r] = acc[dd];
      }
    }
    __syncthreads();

    float r2 = 0.f, ds2 = 0.f, dl2 = 0.f;
    {
      const int a0 = d * 100 + l;
      float x0 = pm[0][a0] + pm[1][a0] + pm[2][a0] + pm[3][a0];
      float x1 = 0.f;
      if (hi) {
        const int a1 = d * 100 + i2;
        x1 = pm[0][a1] + pm[1][a1] + pm[2][a1] + pm[3][a1];
      }
      const int lp1 = (l + 1) & 63, lp2 = (l + 2) & 63;
      float d1x0 = __shfl(x0, lp1), d1x1 = __shfl(x1, lp1);
      float d2x0 = __shfl(x0, lp2), d2x1 = __shfl(x1, lp2);
      float xp1_0 = (l == 63) ? d1x1 : d1x0;
      float xp2_0 = (l >= 62) ? d2x1 : d2x0;
      float xp1_1 = d1x1, xp2_1 = d2x1;
      float c0 = iscan(x0);
      float tt = rdlane(c0, 63);
      float c1 = iscan(hi ? x1 : 0.f) + tt;
#define NU(tp_, tm_, np_, nm_) { \
      float sop = fmaxf(tp_, 0.f), som = fmaxf(tm_, 0.f); \
      float snp = fmaxf(np_, 0.f), snm = fmaxf(nm_, 0.f); \
      float e1 = sop - snp, e2 = som - snm; ds2 += e1 * e1 + e2 * e2; \
      float q1 = snp - (np_), q2 = snm - (nm_); r2 += q1 * q1 + q2 * q2; \
      tp_ = np_; tm_ = nm_; }
      { float np = 1.f - x0, nm = 1.f + x0; NU(t.vp0, t.vm0, np, nm) }
      { float a = 50.f * (xp1_0 - x0); float np = 2.f - a, nm = 2.f + a; NU(t.ap0, t.am0, np, nm) }
      { float j = 2500.f * (xp2_0 - 2.f * xp1_0 + x0); float np = 5.f - j, nm = 5.f + j; NU(t.jp0, t.jm0, np, nm) }
      { float np = bp - 0.02f * c0, nm = bm2 + 0.02f * c0; NU(t.pp0, t.pm0, np, nm) }
      if (hi) {
        { float np = 1.f - x1, nm = 1.f + x1; NU(t.vp1, t.vm1, np, nm) }
        { float np = bp - 0.02f * c1, nm = bm2 + 0.02f * c1; NU(t.pp1, t.pm1, np, nm) }
      }
      if (l <= 34) { float a = 50.f * (xp1_1 - x1); float np = 2.f - a, nm = 2.f + a; NU(t.ap1, t.am1, np, nm) }
      if (l <= 33) { float j = 2500.f * (xp2_1 - 2.f * xp1_1 + x1); float np = 5.f - j, nm = 5.f + j; NU(t.jp1, t.jm1, np, nm) }
#undef NU
    }

    {
      float os0, os1, or0, or1;
      w_phase(t, l, hi, dth, os0, os1, or0, or1);
      lam0 -= or0; dl2 += or0 * or0;
      ru_t[l][d] = lam0 + xs0 + os0;
      if (hi) {
        lam1 -= or1; dl2 += or1 * or1;
        ru_t[i2][d] = lam1 + xs1 + os1;
      }
    }

    r2 = iscan(r2); ds2 = iscan(ds2); dl2 = iscan(dl2);
    if (l == 63) { part[d][it][0] = r2; part[d][it][1] = ds2; part[d][it][2] = dl2; }
  }

  __syncthreads();
  {
    const int a0 = d * 100 + l;
    float x0 = pm[0][a0] + pm[1][a0] + pm[2][a0] + pm[3][a0];
    float* xout = out + (size_t)b * NVARS + d * 100;
    xout[l] = x0;
    if (hi) {
      const int a1 = d * 100 + i2;
      xout[i2] = pm[0][a1] + pm[1][a1] + pm[2][a1] + pm[3][a1];
    }
  }
  if (tid < 20) {
    int it = tid;
    float R2 = 0.f, DS2 = 0.f, DL2 = 0.f;
    for (int dd = 0; dd < 7; ++dd) {
      R2 += part[dd][it][0]; DS2 += part[dd][it][1]; DL2 += part[dd][it][2];
    }
    float pr = sqrtf(R2), fp = sqrtf(DL2) + sqrtf(DS2);
    out[718848 + it * 1024 + b] = pr;
    out[739328 + it * 1024 + b] = fp;
    prfp[it] = pr; prfp[20 + it] = fp;
  }
  __syncthreads();
  if (tid == 0) {
    float ap = 0.f, af = 0.f;
    for (int it = 0; it < 20; ++it) { ap += prfp[it]; af += prfp[20 + it]; }
    out[716800 + b] = af / 20.f;
    out[717824 + b] = ap / 20.f;
  }
}

// =====================================================================
extern "C" void kernel_launch(void* const* d_in, const int* in_sizes, int n_in,
                              void* d_out, int out_size, void* d_ws, size_t ws_size,
                              hipStream_t stream) {
  (void)in_sizes; (void)n_in; (void)out_size;
  const float* input  = (const float*)d_in[0];
  const float* theta  = (const float*)d_in[1];
  const float* vstart = (const float*)d_in[2];
  const float* W1     = (const float*)d_in[3];
  const float* b1     = (const float*)d_in[4];
  const float* W2     = (const float*)d_in[5];
  const float* b2     = (const float*)d_in[6];
  float* out = (float*)d_out;

  float* wsf  = (float*)d_ws;
  double* cid = (double*)d_ws;         // 10000 f64 = 20000 slots
  float* QtT  = wsf + 20000;           // 100*112
  float* med  = wsf + 31200;
  float* rinv = wsf + 31900;

  hipLaunchKernelGGL(qinv_kernel, dim3(1), dim3(128), 0, stream, cid, QtT);
  hipLaunchKernelGGL(quantile_kernel, dim3(700), dim3(256), 0, stream, input, med, rinv);

  const size_t HHI = 32600, HLO = 556888, W2TH = 1081176, W2TL = 4292440,
               OUT2 = 7503704, NEED = 13926232;
  const size_t ANH = OUT2, ANL = OUT2 + 360448, W1TH = OUT2 + 720896, W1TL = OUT2 + 1081344;

  if (ws_size >= NEED * 4ull) {
    ushort* an_h  = (ushort*)(wsf + ANH);
    ushort* an_l  = (ushort*)(wsf + ANL);
    ushort* w1t_h = (ushort*)(wsf + W1TH);
    ushort* w1t_l = (ushort*)(wsf + W1TL);
    ushort* h_h   = (ushort*)(wsf + HHI);
    ushort* h_l   = (ushort*)(wsf + HLO);
    ushort* w2t_h = (ushort*)(wsf + W2TH);
    ushort* w2t_l = (ushort*)(wsf + W2TL);
    float*  out2  = wsf + OUT2;

    hipLaunchKernelGGL(normalize_split, dim3((1024 * 704 + 255) / 256), dim3(256), 0, stream,
                       input, med, rinv, an_h, an_l);
    hipLaunchKernelGGL(tsplit, dim3(22, 32), dim3(32, 8), 0, stream,
                       W1, 700, 1024, 1024, 0, w1t_h, w1t_l, 704);
    hipLaunchKernelGGL(tsplit, dim3(32, 196), dim3(32, 8), 0, stream,
                       W2, 1024, 6958, 6958, 700, w2t_h, w2t_l, 1024);
    // gemm1: nbx=16, nby=16; 256 blocks, chunk=32
    hipLaunchKernelGGL((gemm_mfma<64, 64, 1>), dim3(256), dim3(256), 0, stream,
                       an_h, an_l, w1t_h, w1t_l, b1, 1024,
                       (float*)nullptr, h_h, h_l, 704, 1024, 16, 32);
    // gemm2: nbx=49, nby=16; 784 blocks, chunk=98
    hipLaunchKernelGGL((gemm_mfma<64, 128, 0>), dim3(784), dim3(256), 0, stream,
                       h_h, h_l, w2t_h, w2t_l, b2 + 700, 6258,
                       out2, (ushort*)nullptr, (ushort*)nullptr, 1024, 6272, 16, 98);
    hipLaunchKernelGGL(solver_kernel, dim3(1024), dim3(448), 0, stream,
                       out2, input, theta, vstart, QtT, out, 6272);
  } else {
    float* An   = wsf + 32600;
    float* h    = wsf + 749400;
    float* out2 = wsf + 1797976;
    if (ws_size < (size_t)(1797976 + 6408192) * 4) return;
    hipLaunchKernelGGL(normalize_kernel, dim3(2800), dim3(256), 0, stream, input, med, rinv, An);
    hipLaunchKernelGGL((gemm_kernel<true>), dim3(16, 16), dim3(256), 0, stream,
                       An, NVARS, W1, 1024, b1, h, 1024, 1024, NVARS);
    hipLaunchKernelGGL((gemm_kernel<false>), dim3(98, 16), dim3(256), 0, stream,
                       h, 1024, W2 + 700, 6958, b2 + 700, out2, 6258, 6258, 1024);
    hipLaunchKernelGGL(solver_kernel, dim3(1024), dim3(448), 0, stream,
                       out2, input, theta, vstart, QtT, out, 6258);
  }
}